// Round 11
// baseline (1420.105 us; speedup 1.0000x reference)
//
#include <hip/hip_runtime.h>

typedef __attribute__((ext_vector_type(8))) short short8;
typedef __attribute__((ext_vector_type(4))) float f32x4;

__device__ __forceinline__ unsigned short f2bf(float f) {
  unsigned u = __float_as_uint(f);
  unsigned r = (u + 0x7fffu + ((u >> 16) & 1u)) >> 16;
  return (unsigned short)r;
}
__device__ __forceinline__ float bf2f(unsigned short h) {
  return __uint_as_float(((unsigned)h) << 16);
}

// ---------------------------------------------------------------------------
__global__ __launch_bounds__(256) void bnprep_kernel(
    const float* __restrict__ g, const float* __restrict__ be,
    const float* __restrict__ m, const float* __restrict__ v,
    const float* __restrict__ b, float* __restrict__ A, float* __restrict__ C, int n)
{
  int i = blockIdx.x * 256 + threadIdx.x;
  if (i < n) {
    float s = g[i] / sqrtf(v[i] + 1e-5f);
    A[i] = s;
    C[i] = (b[i] - m[i]) * s + be[i];
  }
}

// Pre-pack conv weights into MFMA B-fragment order:
// unit = (s*NCB + cb)*NF + f ; halves addr = unit*1024 + plane*512 + lane*8 + j
__global__ __launch_bounds__(256) void wprep2_kernel(
    const float* __restrict__ w, unsigned short* __restrict__ wPk, int CO, int CI)
{
  int NCB = CI / 32, NF = CO / 16;
  int total = 9 * NCB * NF * 64;
  int idx = blockIdx.x * 256 + threadIdx.x;
  if (idx >= total) return;
  int lane = idx & 63;
  int unit = idx >> 6;
  int f = unit % NF;
  int cb = (unit / NF) % NCB;
  int s = unit / (NF * NCB);
  int co = f * 16 + (lane & 15);
  int ci0 = cb * 32 + (lane >> 4) * 8;
  long base = (long)unit * 1024 + lane * 8;
  #pragma unroll
  for (int j = 0; j < 8; ++j) {
    float v = w[((long)co * CI + ci0 + j) * 9 + s];
    unsigned short h = f2bf(v);
    unsigned short l = f2bf(v - bf2f(h));
    wPk[base + j] = h;
    wPk[base + 512 + j] = l;
  }
}

// ---------------------------------------------------------------------------
// Fused conv1+conv2 (round-10 proven): conv1 in two 16-channel passes
// (register-pressure bounded), conv2 MFMA + fused maxpool epilogue.
__global__ __launch_bounds__(512, 2) void conv12_kernel(
    const float* __restrict__ xin, const float* __restrict__ cw1,
    const float* __restrict__ A1p, const float* __restrict__ C1p,
    const unsigned short* __restrict__ wPk, const float* __restrict__ Ap,
    const float* __restrict__ Cp, unsigned short* __restrict__ outA)
{
  constexpr int TY = 16, TX = 32;
  constexpr int PXW = TX + 2;              // 34
  constexpr int PXT = (TY + 2) * PXW;      // 612
  constexpr int PLSTR = PXT * 8 + 8;       // 4904 halves
  constexpr int NF = 4;
  __shared__ alignas(16) unsigned short smem[8 * PLSTR];
  __shared__ alignas(16) float sx[2160];
  __shared__ alignas(16) float sw[864];

  const int nwg = gridDim.x;
  const int orig = blockIdx.x;
  const int q = nwg >> 3, r = nwg & 7;
  const int xcd = orig & 7, pos = orig >> 3;
  const int bx = (xcd < r ? xcd * (q + 1) : r * (q + 1) + (xcd - r) * q) + pos;

  const int img = bx >> 1;
  const int tY0 = (bx & 1) * 16;

  const int tid = threadIdx.x;
  const int lane = tid & 63;
  const int lx = lane & 15, kg = lane >> 4;
  const int w = tid >> 6;

  for (int i = tid; i < 2160; i += 512) {
    int c = i / 720, rem = i - c * 720;
    int yy = rem / 36, xx2 = rem - yy * 36;
    int gy = tY0 + yy - 2, gx = xx2 - 2;
    sx[i] = (gy >= 0 && gy < 32 && gx >= 0 && gx < 32)
            ? xin[(long)img * 3072 + c * 1024 + gy * 32 + gx] : 0.f;
  }
  for (int i = tid; i < 864; i += 512) {
    int co = i & 31, kk = i >> 5;
    sw[kk * 32 + co] = cw1[(long)co * 27 + kk];
  }
  __syncthreads();

  #pragma unroll 1
  for (int p = 0; p < 2; ++p) {
    int px = p * 512 + tid;
    if (px < PXT) {
      int ry = px / PXW, rx = px - ry * PXW;
      int gy = tY0 + ry - 1, gx = rx - 1;
      if (gy >= 0 && gy < 32 && gx >= 0 && gx < 32) {
        #pragma unroll 1
        for (int half = 0; half < 2; ++half) {
          float acc[16];
          #pragma unroll
          for (int j = 0; j < 16; ++j) acc[j] = 0.f;
          #pragma unroll
          for (int c = 0; c < 3; ++c) {
            #pragma unroll
            for (int k = 0; k < 9; ++k) {
              int dy = k / 3, dx = k - 3 * (k / 3);
              float iv = sx[c * 720 + (ry + dy) * 36 + rx + dx];
              const float4* w4 = (const float4*)(sw + (c * 9 + k) * 32 + half * 16);
              #pragma unroll
              for (int q2 = 0; q2 < 4; ++q2) {
                float4 wv = w4[q2];
                acc[4 * q2 + 0] += iv * wv.x; acc[4 * q2 + 1] += iv * wv.y;
                acc[4 * q2 + 2] += iv * wv.z; acc[4 * q2 + 3] += iv * wv.w;
              }
            }
          }
          #pragma unroll
          for (int j2 = 0; j2 < 2; ++j2) {
            short8 hv, lv;
            #pragma unroll
            for (int j = 0; j < 8; ++j) {
              int co = half * 16 + j2 * 8 + j;
              float vv = fmaxf(acc[j2 * 8 + j] * A1p[co] + C1p[co], 0.f);
              unsigned short h = f2bf(vv);
              hv[j] = (short)h;
              lv[j] = (short)f2bf(vv - bf2f(h));
            }
            int plane = half * 2 + j2;
            *(short8*)(smem + plane * PLSTR + px * 8) = hv;
            *(short8*)(smem + (plane + 4) * PLSTR + px * 8) = lv;
          }
        }
      } else {
        short8 zz = {0, 0, 0, 0, 0, 0, 0, 0};
        #pragma unroll
        for (int cc = 0; cc < 8; ++cc)
          *(short8*)(smem + cc * PLSTR + px * 8) = zz;
      }
    }
  }
  __syncthreads();

  f32x4 acc[4][4];
  #pragma unroll
  for (int i = 0; i < 4; ++i)
    #pragma unroll
    for (int j = 0; j < 4; ++j) acc[i][j] = (f32x4){0.f, 0.f, 0.f, 0.f};

  for (int s = 0; s < 9; ++s) {
    const int ky = s / 3, kx = s - 3 * (s / 3);
    const long ub = ((long)(s * NF)) * 1024 + lane * 8;
    short8 bh[4], bl[4];
    #pragma unroll
    for (int nf = 0; nf < 4; ++nf) {
      bh[nf] = *(const short8*)(wPk + ub + nf * 1024);
      bl[nf] = *(const short8*)(wPk + ub + nf * 1024 + 512);
    }
    #pragma unroll
    for (int mf = 0; mf < 4; ++mf) {
      const int yoff = mf >> 1;
      const int xb = (mf & 1) * 16;
      const int y = w * 2 + yoff;
      const int pxa = (y + ky) * PXW + xb + kx + lx;
      short8 ah = *(const short8*)(smem + kg * PLSTR + pxa * 8);
      short8 al = *(const short8*)(smem + (kg + 4) * PLSTR + pxa * 8);
      #pragma unroll
      for (int nf = 0; nf < 4; ++nf)
        acc[mf][nf] = __builtin_amdgcn_mfma_f32_16x16x32_bf16(ah, bh[nf], acc[mf][nf], 0, 0, 0);
      #pragma unroll
      for (int nf = 0; nf < 4; ++nf)
        acc[mf][nf] = __builtin_amdgcn_mfma_f32_16x16x32_bf16(ah, bl[nf], acc[mf][nf], 0, 0, 0);
      #pragma unroll
      for (int nf = 0; nf < 4; ++nf)
        acc[mf][nf] = __builtin_amdgcn_mfma_f32_16x16x32_bf16(al, bh[nf], acc[mf][nf], 0, 0, 0);
    }
  }
  __syncthreads();

  float Ar[4], Cr[4];
  #pragma unroll
  for (int nf = 0; nf < 4; ++nf) {
    int co = nf * 16 + lx;
    Ar[nf] = Ap[co]; Cr[nf] = Cp[co];
  }

  unsigned short* slice = smem + w * 2048;
  const int py = (tY0 >> 1) + w;
  #pragma unroll
  for (int xf = 0; xf < 2; ++xf) {
    #pragma unroll
    for (int rp = 0; rp < 2; ++rp) {
      int ox = xf * 8 + 2 * kg + rp;
      #pragma unroll
      for (int nf = 0; nf < 4; ++nf) {
        float v0 = fmaxf(fmaxf(acc[xf][nf][2 * rp], acc[xf][nf][2 * rp + 1]),
                         fmaxf(acc[xf + 2][nf][2 * rp], acc[xf + 2][nf][2 * rp + 1]));
        float vv = fmaxf(v0 * Ar[nf] + Cr[nf], 0.f);
        unsigned short h = f2bf(vv);
        unsigned short l = f2bf(vv - bf2f(h));
        slice[(ox * 2 + 0) * 64 + nf * 16 + lx] = h;
        slice[(ox * 2 + 1) * 64 + nf * 16 + lx] = l;
      }
    }
  }
  #pragma unroll
  for (int v = 0; v < 4; ++v) {
    int hoff = lane * 8 + v * 512;
    int x2 = hoff >> 7, rem = hoff & 127;
    int seg = rem >> 6, inner = rem & 63;
    short8 d = *(const short8*)(slice + hoff);
    *(short8*)(outA + ((long)img * 256 + py * 16 + x2) * 128 + seg * 64 + inner) = d;
  }
}

// ---------------------------------------------------------------------------
// Unified split-bf16 MFMA conv (round-8 proven).
template<int H, int CI, int CO, int COB, int TY, int TX, int MODE>
__global__ __launch_bounds__(512, 2) void convmf4_kernel(
    const unsigned short* __restrict__ actIn, const unsigned short* __restrict__ wPk,
    const float* __restrict__ Ap, const float* __restrict__ Cp,
    void* __restrict__ outP)
{
  constexpr int NCB = CI / 32;
  constexpr int NF  = CO / 16;
  constexpr int NCOG = COB / 64;
  constexpr int NPXG = 8 / NCOG;
  constexpr int ROWS_PG = TY / NPXG;
  constexpr int FRX = TX / 16;
  constexpr int PXW = TX + 2;
  constexpr int PXT = (TY + 2) * PXW;
  constexpr int PLSTR = PXT * 8 + 8;
  constexpr int TILES_Y = H / TY;
  constexpr int CBLK = CO / COB;
  constexpr int TPI = TILES_Y * CBLK;
  constexpr int PIX_IN = 2 * CI;
  __shared__ alignas(16) unsigned short smem[8 * PLSTR];

  const int nwg = gridDim.x;
  const int orig = blockIdx.x;
  const int q = nwg >> 3, r = nwg & 7;
  const int xcd = orig & 7, pos = orig >> 3;
  const int bx = (xcd < r ? xcd * (q + 1) : r * (q + 1) + (xcd - r) * q) + pos;

  const int img = bx / TPI;
  const int sub = bx % TPI;
  const int tY0 = (sub % TILES_Y) * TY;
  const int blkco = sub / TILES_Y;

  const int tid = threadIdx.x;
  const int lane = tid & 63;
  const int lx = lane & 15, kg = lane >> 4;
  const int w = tid >> 6;
  const int pxg = w % NPXG, cog = w / NPXG;

  f32x4 acc[4][4];
  #pragma unroll
  for (int i = 0; i < 4; ++i)
    #pragma unroll
    for (int j = 0; j < 4; ++j) acc[i][j] = (f32x4){0.f, 0.f, 0.f, 0.f};

  for (int cb = 0; cb < NCB; ++cb) {
    if (cb) __syncthreads();
    for (int t2 = tid; t2 < PXT * 8; t2 += 512) {
      int px = t2 >> 3, c = t2 & 7;
      int ry = px / PXW, rx = px - ry * PXW;
      int gy = tY0 + ry - 1, gx = rx - 1;
      float4 v = (float4){0.f, 0.f, 0.f, 0.f};
      if (gy >= 0 && gy < H && gx >= 0 && gx < H) {
        int coff = (c < 4) ? (cb * 32 + c * 8) : (CI + cb * 32 + (c - 4) * 8);
        v = *(const float4*)(actIn + ((long)img * H * H + gy * H + gx) * PIX_IN + coff);
      }
      *(float4*)(smem + c * PLSTR + px * 8) = v;
    }
    __syncthreads();

    for (int s = 0; s < 9; ++s) {
      const int ky = s / 3, kx = s - 3 * (s / 3);
      const long ub = ((long)(s * NCB + cb) * NF + blkco * (COB / 16) + cog * 4) * 1024
                      + lane * 8;
      short8 bh[4], bl[4];
      #pragma unroll
      for (int nf = 0; nf < 4; ++nf) {
        bh[nf] = *(const short8*)(wPk + ub + nf * 1024);
        bl[nf] = *(const short8*)(wPk + ub + nf * 1024 + 512);
      }
      #pragma unroll
      for (int mf = 0; mf < 4; ++mf) {
        const int yoff = (FRX == 2) ? (mf >> 1) : mf;
        const int xb = (FRX == 2) ? ((mf & 1) * 16) : 0;
        const int y = pxg * ROWS_PG + yoff;
        const int pxa = (y + ky) * PXW + xb + kx + lx;
        short8 ah = *(const short8*)(smem + kg * PLSTR + pxa * 8);
        short8 al = *(const short8*)(smem + (kg + 4) * PLSTR + pxa * 8);
        #pragma unroll
        for (int nf = 0; nf < 4; ++nf)
          acc[mf][nf] = __builtin_amdgcn_mfma_f32_16x16x32_bf16(ah, bh[nf], acc[mf][nf], 0, 0, 0);
        #pragma unroll
        for (int nf = 0; nf < 4; ++nf)
          acc[mf][nf] = __builtin_amdgcn_mfma_f32_16x16x32_bf16(ah, bl[nf], acc[mf][nf], 0, 0, 0);
        #pragma unroll
        for (int nf = 0; nf < 4; ++nf)
          acc[mf][nf] = __builtin_amdgcn_mfma_f32_16x16x32_bf16(al, bh[nf], acc[mf][nf], 0, 0, 0);
      }
    }
  }
  __syncthreads();

  float Ar[4], Cr[4];
  #pragma unroll
  for (int nf = 0; nf < 4; ++nf) {
    int co = blkco * COB + cog * 64 + nf * 16 + lx;
    Ar[nf] = Ap[co]; Cr[nf] = Cp[co];
  }

  if (MODE == 0) {
    unsigned short* outA = (unsigned short*)outP;
    unsigned short* slice = smem + w * 2048;
    #pragma unroll
    for (int mf = 0; mf < 4; ++mf) {
      int y = tY0 + pxg * ROWS_PG + mf;
      #pragma unroll
      for (int rr = 0; rr < 4; ++rr) {
        int x = 4 * kg + rr;
        #pragma unroll
        for (int nf = 0; nf < 4; ++nf) {
          float vv = fmaxf(acc[mf][nf][rr] * Ar[nf] + Cr[nf], 0.f);
          unsigned short h = f2bf(vv);
          unsigned short l = f2bf(vv - bf2f(h));
          slice[(x * 2 + 0) * 64 + nf * 16 + lx] = h;
          slice[(x * 2 + 1) * 64 + nf * 16 + lx] = l;
        }
      }
      #pragma unroll
      for (int v = 0; v < 4; ++v) {
        int hoff = lane * 8 + v * 512;
        int x2 = hoff >> 7, rem = hoff & 127;
        int seg = rem >> 6, inner = rem & 63;
        short8 d = *(const short8*)(slice + hoff);
        *(short8*)(outA + ((long)img * 256 + y * 16 + x2) * (2 * CO)
                   + seg * CO + blkco * COB + cog * 64 + inner) = d;
      }
    }
  } else {
    float psum[4] = {0.f, 0.f, 0.f, 0.f};
    #pragma unroll
    for (int nf = 0; nf < 4; ++nf) {
      #pragma unroll
      for (int mfp = 0; mfp < 2; ++mfp) {
        #pragma unroll
        for (int rp = 0; rp < 2; ++rp) {
          float v = fmaxf(fmaxf(acc[2 * mfp][nf][2 * rp], acc[2 * mfp][nf][2 * rp + 1]),
                          fmaxf(acc[2 * mfp + 1][nf][2 * rp], acc[2 * mfp + 1][nf][2 * rp + 1]));
          psum[nf] += fmaxf(v * Ar[nf] + Cr[nf], 0.f);
        }
      }
    }
    #pragma unroll
    for (int nf = 0; nf < 4; ++nf) {
      psum[nf] += __shfl_xor(psum[nf], 16);
      psum[nf] += __shfl_xor(psum[nf], 32);
    }
    __syncthreads();
    float* sR = (float*)smem;
    if (kg == 0) {
      #pragma unroll
      for (int nf = 0; nf < 4; ++nf) sR[w * 64 + nf * 16 + lx] = psum[nf];
    }
    __syncthreads();
    if (tid < COB) {
      int ct = tid >> 6, ci_ = tid & 63;
      float s = 0.f;
      #pragma unroll
      for (int p = 0; p < NPXG; ++p) s += sR[(ct * NPXG + p) * 64 + ci_];
      ((float*)outP)[(long)img * 256 + blkco * COB + tid] = s * (1.f / 64.f);
    }
  }
}

// ---------------------------------------------------------------------------
// heads (unchanged)
__global__ __launch_bounds__(256) void heads2_kernel(
    const float* __restrict__ feats, const float* __restrict__ gw1,
    const float* __restrict__ gb1, const float* __restrict__ gw2,
    const float* __restrict__ gb2, const float* __restrict__ clsw,
    const float* __restrict__ clsb, const float* __restrict__ usage,
    float* __restrict__ logits_e, float* __restrict__ rs_out)
{
  __shared__ float sF[64 * 257];
  __shared__ float sLg[4 * 64 * 10];
  __shared__ float sRed[4 * 64];
  const int tid = threadIdx.x;
  const int b0 = blockIdx.x * 64;
  const int e  = blockIdx.y;

  for (int idx = tid; idx < 64 * 64; idx += 256) {
    int t = idx >> 6, dg = idx & 63;
    float4 v = ((const float4*)(feats + (long)(b0 + t) * 256))[dg];
    float* p = sF + t * 257 + dg * 4;
    p[0] = v.x; p[1] = v.y; p[2] = v.z; p[3] = v.w;
  }
  __syncthreads();

  const int t  = tid & 63;
  const int hw = __builtin_amdgcn_readfirstlane(tid >> 6);

  {
    float acc[10];
    #pragma unroll
    for (int c = 0; c < 10; ++c) acc[c] = 0.f;
    const float* fp = sF + t * 257 + hw * 64;
    const float* cw = clsw + (long)e * 2560 + hw * 64;
    for (int dd = 0; dd < 64; ++dd) {
      float f = fp[dd];
      #pragma unroll
      for (int c = 0; c < 10; ++c) acc[c] += f * cw[c * 256 + dd];
    }
    #pragma unroll
    for (int c = 0; c < 10; ++c) sLg[(hw * 64 + t) * 10 + c] = acc[c];
  }
  {
    float gacc[32];
    #pragma unroll
    for (int j = 0; j < 32; ++j) gacc[j] = 0.f;
    const float* wb = gw1 + ((long)e * 256) * 128 + hw * 32;
    const float* fp = sF + t * 257;
    for (int d = 0; d < 256; ++d) {
      float f = fp[d];
      const float4* w4 = (const float4*)(wb + (long)d * 128);
      #pragma unroll
      for (int qq = 0; qq < 8; ++qq) {
        float4 wv = w4[qq];
        gacc[4 * qq + 0] += f * wv.x; gacc[4 * qq + 1] += f * wv.y;
        gacc[4 * qq + 2] += f * wv.z; gacc[4 * qq + 3] += f * wv.w;
      }
    }
    float s = 0.f;
    const float* b1 = gb1 + e * 128 + hw * 32;
    const float* w2 = gw2 + e * 128 + hw * 32;
    #pragma unroll
    for (int j = 0; j < 32; ++j) s += fmaxf(gacc[j] + b1[j], 0.f) * w2[j];
    sRed[hw * 64 + t] = s;
  }
  __syncthreads();

  if (tid < 64) {
    float es = (sRed[t] + sRed[64 + t] + sRed[128 + t] + sRed[192 + t] + gb2[e]) * 0.5f;
    float lg[10];
    #pragma unroll
    for (int c = 0; c < 10; ++c)
      lg[c] = sLg[t * 10 + c] + sLg[(64 + t) * 10 + c]
            + sLg[(128 + t) * 10 + c] + sLg[(192 + t) * 10 + c] + clsb[e * 10 + c];
    float mx = lg[0];
    #pragma unroll
    for (int c = 1; c < 10; ++c) mx = fmaxf(mx, lg[c]);
    float S = 0.f, ps[10];
    #pragma unroll
    for (int c = 0; c < 10; ++c) { ps[c] = expf(lg[c] - mx); S += ps[c]; }
    float inv = 1.f / S, ent = 0.f;
    #pragma unroll
    for (int c = 0; c < 10; ++c) { float p = ps[c] * inv; ent -= p * logf(fmaxf(p, 1e-12f)); }
    float rsv = 0.6f * es + 0.4f * (-ent) - 2.0f * usage[e];
    rs_out[(long)(b0 + t) * 16 + e] = rsv;
    #pragma unroll
    for (int c = 0; c < 10; ++c)
      logits_e[((long)(b0 + t) * 16 + e) * 10 + c] = lg[c];
  }
}

__global__ __launch_bounds__(1024) void sort_kernel(
    const float* __restrict__ rs, unsigned* __restrict__ sortedIdx)
{
  __shared__ unsigned long long sk[2048];
  const int e = blockIdx.x;
  const unsigned tid = threadIdx.x;
  for (int i = tid; i < 2048; i += 1024) {
    float f = rs[(long)i * 16 + e];
    unsigned u = __float_as_uint(f);
    u ^= (u >> 31) ? 0xFFFFFFFFu : 0x80000000u;
    sk[i] = ((unsigned long long)(~u) << 32) | (unsigned)i;
  }
  for (unsigned k = 2; k <= 2048; k <<= 1) {
    for (unsigned j = k >> 1; j > 0; j >>= 1) {
      __syncthreads();
      unsigned i = ((tid & ~(j - 1)) << 1) | (tid & (j - 1));
      unsigned p = i | j;
      bool asc = ((i & k) == 0);
      unsigned long long a = sk[i], b = sk[p];
      if ((a > b) == asc) { sk[i] = b; sk[p] = a; }
    }
  }
  __syncthreads();
  for (int i = tid; i < 2048; i += 1024)
    sortedIdx[(long)e * 2048 + i] = (unsigned)(sk[i] & 0xFFFFFFFFull);
}

// Single-wave routing: wave-synchronous ballot scan with early exit.
// Claim set provably identical to the 1024-thread version (claims need
// pre < ntc; once taken >= ntc no further claims can occur).
__global__ __launch_bounds__(64) void routing2_kernel(
    const unsigned* __restrict__ sortedIdx, const float* __restrict__ rs,
    unsigned* __restrict__ dmaskOut)
{
  __shared__ unsigned char sAvail[2048];
  __shared__ unsigned sDm[2048];
  __shared__ int sLoads[16];
  const int lane = threadIdx.x;
  for (int i = lane; i < 2048; i += 64) { sAvail[i] = 1; sDm[i] = 0; }
  if (lane < 16) sLoads[lane] = 0;
  __syncthreads();

  int vc = 2048;   // uniform across lanes
  for (int it = 0; it < 3; ++it) {
    for (int j = 0; j < 16; ++j) {
      int lj = sLoads[j];                 // uniform LDS broadcast read
      int rc = 256 - lj; if (rc < 0) rc = 0;
      int ntc = 0;
      if (rc > 0 && vc > 0) {
        int a = rc < vc ? rc : vc;
        int b2 = vc < 102 ? vc : 102;
        ntc = a > b2 ? a : b2;
      }
      if (ntc > 0) {
        const unsigned* se = sortedIdx + (long)j * 2048;
        int taken = 0;
        for (int base = 0; base < 2048; base += 64) {
          if (taken >= ntc) break;        // uniform early exit
          unsigned tok = se[base + lane];
          int fl = sAvail[tok] ? 1 : 0;
          unsigned long long bm = __ballot(fl);
          int pre = taken + __popcll(bm & ((1ull << lane) - 1ull));
          if (fl && pre < ntc) { sAvail[tok] = 0; sDm[tok] |= (1u << j); }
          taken += (int)__popcll(bm);
          __syncthreads();                // order LDS writes before next round
        }
        if (lane == 0) sLoads[j] = lj + ntc;
        vc -= ntc;
        __syncthreads();
      }
    }
  }

  // fallback (vc==0 for this workload; kept for correctness)
  if (vc > 0) {
    if (lane == 0) {
      for (int i = 0; i < 2048; ++i) {
        if (!sAvail[i]) continue;
        float s0 = -3.4e38f, s1 = s0, s2 = s0; int e0 = 0, e1 = 0, e2 = 0;
        for (int e = 0; e < 16; ++e) {
          float s = rs[i * 16 + e];
          if (s > s0)      { s2 = s1; e2 = e1; s1 = s0; e1 = e0; s0 = s; e0 = e; }
          else if (s > s1) { s2 = s1; e2 = e1; s1 = s;  e1 = e; }
          else if (s > s2) { s2 = s;  e2 = e; }
        }
        int best = e0, bl = sLoads[e0];
        if (sLoads[e1] < bl) { best = e1; bl = sLoads[e1]; }
        if (sLoads[e2] < bl) { best = e2; bl = sLoads[e2]; }
        sDm[i] |= (1u << best);
        sLoads[best] += 1;
      }
    }
    __syncthreads();
  }

  for (int i = lane; i < 2048; i += 64) dmaskOut[i] = sDm[i];
}

// combine: softmax-weighted logits + expands dmask into the D output.
__global__ __launch_bounds__(256) void combine_kernel(
    const unsigned* __restrict__ dmask, const float* __restrict__ rs,
    const float* __restrict__ L, float* __restrict__ out, float* __restrict__ Dout)
{
  int i = blockIdx.x * 256 + threadIdx.x;
  if (i >= 2048) return;
  unsigned dm = dmask[i];
  float r[16];
  #pragma unroll
  for (int e = 0; e < 16; ++e) r[e] = rs[i * 16 + e];
  float mx = -3.4e38f;
  #pragma unroll
  for (int e = 0; e < 16; ++e) {
    float v = ((dm >> e) & 1u) ? r[e] : 0.0f;
    mx = fmaxf(mx, v);
  }
  float w[16], S = 0.f;
  #pragma unroll
  for (int e = 0; e < 16; ++e) {
    w[e] = ((dm >> e) & 1u) ? expf(r[e] - mx) : 0.0f;
    S += w[e];
  }
  float inv = 1.f / S;
  #pragma unroll
  for (int c = 0; c < 10; ++c) {
    float a = 0.f;
    #pragma unroll
    for (int e = 0; e < 16; ++e) a += w[e] * L[((long)i * 16 + e) * 10 + c];
    out[i * 10 + c] = a * inv;
  }
  #pragma unroll
  for (int e = 0; e < 16; ++e)
    Dout[(long)i * 16 + e] = ((dm >> e) & 1u) ? 1.0f : 0.0f;
}

// ---------------------------------------------------------------------------
extern "C" void kernel_launch(void* const* d_in, const int* in_sizes, int n_in,
                              void* d_out, int out_size, void* d_ws, size_t ws_size,
                              hipStream_t stream)
{
  const float* x    = (const float*)d_in[0];
  const float* cw1  = (const float*)d_in[1];
  const float* cb1  = (const float*)d_in[2];
  const float* g1   = (const float*)d_in[3];
  const float* be1  = (const float*)d_in[4];
  const float* m1   = (const float*)d_in[5];
  const float* v1   = (const float*)d_in[6];
  const float* cw2  = (const float*)d_in[7];
  const float* cb2  = (const float*)d_in[8];
  const float* g2   = (const float*)d_in[9];
  const float* be2  = (const float*)d_in[10];
  const float* m2   = (const float*)d_in[11];
  const float* v2   = (const float*)d_in[12];
  const float* cw3  = (const float*)d_in[13];
  const float* cb3  = (const float*)d_in[14];
  const float* g3   = (const float*)d_in[15];
  const float* be3  = (const float*)d_in[16];
  const float* m3   = (const float*)d_in[17];
  const float* v3   = (const float*)d_in[18];
  const float* cw4  = (const float*)d_in[19];
  const float* cb4  = (const float*)d_in[20];
  const float* g4   = (const float*)d_in[21];
  const float* be4  = (const float*)d_in[22];
  const float* m4   = (const float*)d_in[23];
  const float* v4   = (const float*)d_in[24];
  const float* gw1  = (const float*)d_in[25];
  const float* gb1  = (const float*)d_in[26];
  const float* gw2  = (const float*)d_in[27];
  const float* gb2  = (const float*)d_in[28];
  const float* clsw = (const float*)d_in[29];
  const float* clsb = (const float*)d_in[30];
  const float* usage = (const float*)d_in[31];

  float* out = (float*)d_out;
  float* ws  = (float*)d_ws;

  float* A1 = ws + 0;   float* C1 = ws + 32;
  float* A2 = ws + 64;  float* C2 = ws + 128;
  float* A3 = ws + 192; float* C3 = ws + 320;
  float* A4 = ws + 448; float* C4 = ws + 704;
  float* feats   = ws + 1024;                       // 2048*256
  float* logitsE = ws + 525312;                     // 2048*16*10
  unsigned* sortedIdx = (unsigned*)(ws + 852992);   // 16*2048
  unsigned* dmask     = (unsigned*)(ws + 885760);   // 2048
  unsigned short* wPk2 = (unsigned short*)(ws + 887808);   // 36 units  * 1024 halves
  unsigned short* wPk3 = (unsigned short*)(ws + 906240);   // 144 units * 1024
  unsigned short* wPk4 = (unsigned short*)(ws + 979968);   // 576 units * 1024
  const long bufBase = 1274880;

  long wsFloats = (long)(ws_size / 4);
  long availF = wsFloats - bufBase;
  long chunkL = availF / 49152;   // per-img: bufA 32768 f + bufB 16384 f
  int chunk = (int)(chunkL < 1 ? 1 : (chunkL > 2048 ? 2048 : chunkL));

  bnprep_kernel<<<1, 256, 0, stream>>>(g1, be1, m1, v1, cb1, A1, C1, 32);
  bnprep_kernel<<<1, 256, 0, stream>>>(g2, be2, m2, v2, cb2, A2, C2, 64);
  bnprep_kernel<<<1, 256, 0, stream>>>(g3, be3, m3, v3, cb3, A3, C3, 128);
  bnprep_kernel<<<1, 256, 0, stream>>>(g4, be4, m4, v4, cb4, A4, C4, 256);
  wprep2_kernel<<<(2304 + 255) / 256, 256, 0, stream>>>(cw2, wPk2, 64, 32);
  wprep2_kernel<<<(9216 + 255) / 256, 256, 0, stream>>>(cw3, wPk3, 128, 64);
  wprep2_kernel<<<(36864 + 255) / 256, 256, 0, stream>>>(cw4, wPk4, 256, 128);

  unsigned short* bufA = (unsigned short*)(ws + bufBase);
  unsigned short* bufB = bufA + (long)chunk * 65536;

  for (int ib = 0; ib < 2048; ib += chunk) {
    int n = 2048 - ib; if (n > chunk) n = chunk;
    // fused conv1+conv2: x -> act2 (act1 stays in LDS)
    conv12_kernel<<<dim3(n * 2), 512, 0, stream>>>(
        x + (long)ib * 3072, cw1, A1, C1, wPk2, A2, C2, bufB);
    // conv3: 16x16, 64->128ch, 1 block/img (no co-split), plain store -> act3
    convmf4_kernel<16, 64, 128, 128, 16, 16, 0>
        <<<dim3(n), 512, 0, stream>>>(bufB, wPk3, A3, C3, bufA);
    // conv4: 16x16, 128->256ch, 2 co-blocks/img, pool+avg -> feats
    convmf4_kernel<16, 128, 256, 128, 16, 16, 2>
        <<<dim3(n * 2), 512, 0, stream>>>(bufA, wPk4, A4, C4, feats + (long)ib * 256);
  }

  float* rsOut = out + 20480;
  heads2_kernel<<<dim3(32, 16), 256, 0, stream>>>(feats, gw1, gb1, gw2, gb2,
                                                  clsw, clsb, usage, logitsE, rsOut);
  sort_kernel<<<16, 1024, 0, stream>>>(rsOut, sortedIdx);
  routing2_kernel<<<1, 64, 0, stream>>>(sortedIdx, rsOut, dmask);
  combine_kernel<<<8, 256, 0, stream>>>(dmask, rsOut, logitsE, out, out + 53248);
}

// Round 12
// 1403.696 us; speedup vs baseline: 1.0117x; 1.0117x over previous
//
#include <hip/hip_runtime.h>

typedef __attribute__((ext_vector_type(8))) short short8;
typedef __attribute__((ext_vector_type(4))) float f32x4;

__device__ __forceinline__ unsigned short f2bf(float f) {
  unsigned u = __float_as_uint(f);
  unsigned r = (u + 0x7fffu + ((u >> 16) & 1u)) >> 16;
  return (unsigned short)r;
}
__device__ __forceinline__ float bf2f(unsigned short h) {
  return __uint_as_float(((unsigned)h) << 16);
}

// ---------------------------------------------------------------------------
__global__ __launch_bounds__(256) void bnprep_kernel(
    const float* __restrict__ g, const float* __restrict__ be,
    const float* __restrict__ m, const float* __restrict__ v,
    const float* __restrict__ b, float* __restrict__ A, float* __restrict__ C, int n)
{
  int i = blockIdx.x * 256 + threadIdx.x;
  if (i < n) {
    float s = g[i] / sqrtf(v[i] + 1e-5f);
    A[i] = s;
    C[i] = (b[i] - m[i]) * s + be[i];
  }
}

// Pre-pack conv weights into MFMA B-fragment order:
// unit = (s*NCB + cb)*NF + f ; halves addr = unit*1024 + plane*512 + lane*8 + j
__global__ __launch_bounds__(256) void wprep2_kernel(
    const float* __restrict__ w, unsigned short* __restrict__ wPk, int CO, int CI)
{
  int NCB = CI / 32, NF = CO / 16;
  int total = 9 * NCB * NF * 64;
  int idx = blockIdx.x * 256 + threadIdx.x;
  if (idx >= total) return;
  int lane = idx & 63;
  int unit = idx >> 6;
  int f = unit % NF;
  int cb = (unit / NF) % NCB;
  int s = unit / (NF * NCB);
  int co = f * 16 + (lane & 15);
  int ci0 = cb * 32 + (lane >> 4) * 8;
  long base = (long)unit * 1024 + lane * 8;
  #pragma unroll
  for (int j = 0; j < 8; ++j) {
    float v = w[((long)co * CI + ci0 + j) * 9 + s];
    unsigned short h = f2bf(v);
    unsigned short l = f2bf(v - bf2f(h));
    wPk[base + j] = h;
    wPk[base + 512 + j] = l;
  }
}

// ---------------------------------------------------------------------------
// Fused conv1+conv2 (round-10 proven).
__global__ __launch_bounds__(512, 2) void conv12_kernel(
    const float* __restrict__ xin, const float* __restrict__ cw1,
    const float* __restrict__ A1p, const float* __restrict__ C1p,
    const unsigned short* __restrict__ wPk, const float* __restrict__ Ap,
    const float* __restrict__ Cp, unsigned short* __restrict__ outA)
{
  constexpr int TY = 16, TX = 32;
  constexpr int PXW = TX + 2;
  constexpr int PXT = (TY + 2) * PXW;
  constexpr int PLSTR = PXT * 8 + 8;
  constexpr int NF = 4;
  __shared__ alignas(16) unsigned short smem[8 * PLSTR];
  __shared__ alignas(16) float sx[2160];
  __shared__ alignas(16) float sw[864];

  const int nwg = gridDim.x;
  const int orig = blockIdx.x;
  const int q = nwg >> 3, r = nwg & 7;
  const int xcd = orig & 7, pos = orig >> 3;
  const int bx = (xcd < r ? xcd * (q + 1) : r * (q + 1) + (xcd - r) * q) + pos;

  const int img = bx >> 1;
  const int tY0 = (bx & 1) * 16;

  const int tid = threadIdx.x;
  const int lane = tid & 63;
  const int lx = lane & 15, kg = lane >> 4;
  const int w = tid >> 6;

  for (int i = tid; i < 2160; i += 512) {
    int c = i / 720, rem = i - c * 720;
    int yy = rem / 36, xx2 = rem - yy * 36;
    int gy = tY0 + yy - 2, gx = xx2 - 2;
    sx[i] = (gy >= 0 && gy < 32 && gx >= 0 && gx < 32)
            ? xin[(long)img * 3072 + c * 1024 + gy * 32 + gx] : 0.f;
  }
  for (int i = tid; i < 864; i += 512) {
    int co = i & 31, kk = i >> 5;
    sw[kk * 32 + co] = cw1[(long)co * 27 + kk];
  }
  __syncthreads();

  #pragma unroll 1
  for (int p = 0; p < 2; ++p) {
    int px = p * 512 + tid;
    if (px < PXT) {
      int ry = px / PXW, rx = px - ry * PXW;
      int gy = tY0 + ry - 1, gx = rx - 1;
      if (gy >= 0 && gy < 32 && gx >= 0 && gx < 32) {
        #pragma unroll 1
        for (int half = 0; half < 2; ++half) {
          float acc[16];
          #pragma unroll
          for (int j = 0; j < 16; ++j) acc[j] = 0.f;
          #pragma unroll
          for (int c = 0; c < 3; ++c) {
            #pragma unroll
            for (int k = 0; k < 9; ++k) {
              int dy = k / 3, dx = k - 3 * (k / 3);
              float iv = sx[c * 720 + (ry + dy) * 36 + rx + dx];
              const float4* w4 = (const float4*)(sw + (c * 9 + k) * 32 + half * 16);
              #pragma unroll
              for (int q2 = 0; q2 < 4; ++q2) {
                float4 wv = w4[q2];
                acc[4 * q2 + 0] += iv * wv.x; acc[4 * q2 + 1] += iv * wv.y;
                acc[4 * q2 + 2] += iv * wv.z; acc[4 * q2 + 3] += iv * wv.w;
              }
            }
          }
          #pragma unroll
          for (int j2 = 0; j2 < 2; ++j2) {
            short8 hv, lv;
            #pragma unroll
            for (int j = 0; j < 8; ++j) {
              int co = half * 16 + j2 * 8 + j;
              float vv = fmaxf(acc[j2 * 8 + j] * A1p[co] + C1p[co], 0.f);
              unsigned short h = f2bf(vv);
              hv[j] = (short)h;
              lv[j] = (short)f2bf(vv - bf2f(h));
            }
            int plane = half * 2 + j2;
            *(short8*)(smem + plane * PLSTR + px * 8) = hv;
            *(short8*)(smem + (plane + 4) * PLSTR + px * 8) = lv;
          }
        }
      } else {
        short8 zz = {0, 0, 0, 0, 0, 0, 0, 0};
        #pragma unroll
        for (int cc = 0; cc < 8; ++cc)
          *(short8*)(smem + cc * PLSTR + px * 8) = zz;
      }
    }
  }
  __syncthreads();

  f32x4 acc[4][4];
  #pragma unroll
  for (int i = 0; i < 4; ++i)
    #pragma unroll
    for (int j = 0; j < 4; ++j) acc[i][j] = (f32x4){0.f, 0.f, 0.f, 0.f};

  for (int s = 0; s < 9; ++s) {
    const int ky = s / 3, kx = s - 3 * (s / 3);
    const long ub = ((long)(s * NF)) * 1024 + lane * 8;
    short8 bh[4], bl[4];
    #pragma unroll
    for (int nf = 0; nf < 4; ++nf) {
      bh[nf] = *(const short8*)(wPk + ub + nf * 1024);
      bl[nf] = *(const short8*)(wPk + ub + nf * 1024 + 512);
    }
    #pragma unroll
    for (int mf = 0; mf < 4; ++mf) {
      const int yoff = mf >> 1;
      const int xb = (mf & 1) * 16;
      const int y = w * 2 + yoff;
      const int pxa = (y + ky) * PXW + xb + kx + lx;
      short8 ah = *(const short8*)(smem + kg * PLSTR + pxa * 8);
      short8 al = *(const short8*)(smem + (kg + 4) * PLSTR + pxa * 8);
      #pragma unroll
      for (int nf = 0; nf < 4; ++nf)
        acc[mf][nf] = __builtin_amdgcn_mfma_f32_16x16x32_bf16(ah, bh[nf], acc[mf][nf], 0, 0, 0);
      #pragma unroll
      for (int nf = 0; nf < 4; ++nf)
        acc[mf][nf] = __builtin_amdgcn_mfma_f32_16x16x32_bf16(ah, bl[nf], acc[mf][nf], 0, 0, 0);
      #pragma unroll
      for (int nf = 0; nf < 4; ++nf)
        acc[mf][nf] = __builtin_amdgcn_mfma_f32_16x16x32_bf16(al, bh[nf], acc[mf][nf], 0, 0, 0);
    }
  }
  __syncthreads();

  float Ar[4], Cr[4];
  #pragma unroll
  for (int nf = 0; nf < 4; ++nf) {
    int co = nf * 16 + lx;
    Ar[nf] = Ap[co]; Cr[nf] = Cp[co];
  }

  unsigned short* slice = smem + w * 2048;
  const int py = (tY0 >> 1) + w;
  #pragma unroll
  for (int xf = 0; xf < 2; ++xf) {
    #pragma unroll
    for (int rp = 0; rp < 2; ++rp) {
      int ox = xf * 8 + 2 * kg + rp;
      #pragma unroll
      for (int nf = 0; nf < 4; ++nf) {
        float v0 = fmaxf(fmaxf(acc[xf][nf][2 * rp], acc[xf][nf][2 * rp + 1]),
                         fmaxf(acc[xf + 2][nf][2 * rp], acc[xf + 2][nf][2 * rp + 1]));
        float vv = fmaxf(v0 * Ar[nf] + Cr[nf], 0.f);
        unsigned short h = f2bf(vv);
        unsigned short l = f2bf(vv - bf2f(h));
        slice[(ox * 2 + 0) * 64 + nf * 16 + lx] = h;
        slice[(ox * 2 + 1) * 64 + nf * 16 + lx] = l;
      }
    }
  }
  #pragma unroll
  for (int v = 0; v < 4; ++v) {
    int hoff = lane * 8 + v * 512;
    int x2 = hoff >> 7, rem = hoff & 127;
    int seg = rem >> 6, inner = rem & 63;
    short8 d = *(const short8*)(slice + hoff);
    *(short8*)(outA + ((long)img * 256 + py * 16 + x2) * 128 + seg * 64 + inner) = d;
  }
}

// ---------------------------------------------------------------------------
// Unified split-bf16 MFMA conv (round-8 proven) -- used for conv3.
template<int H, int CI, int CO, int COB, int TY, int TX, int MODE>
__global__ __launch_bounds__(512, 2) void convmf4_kernel(
    const unsigned short* __restrict__ actIn, const unsigned short* __restrict__ wPk,
    const float* __restrict__ Ap, const float* __restrict__ Cp,
    void* __restrict__ outP)
{
  constexpr int NCB = CI / 32;
  constexpr int NF  = CO / 16;
  constexpr int NCOG = COB / 64;
  constexpr int NPXG = 8 / NCOG;
  constexpr int ROWS_PG = TY / NPXG;
  constexpr int FRX = TX / 16;
  constexpr int PXW = TX + 2;
  constexpr int PXT = (TY + 2) * PXW;
  constexpr int PLSTR = PXT * 8 + 8;
  constexpr int TILES_Y = H / TY;
  constexpr int CBLK = CO / COB;
  constexpr int TPI = TILES_Y * CBLK;
  constexpr int PIX_IN = 2 * CI;
  __shared__ alignas(16) unsigned short smem[8 * PLSTR];

  const int nwg = gridDim.x;
  const int orig = blockIdx.x;
  const int q = nwg >> 3, r = nwg & 7;
  const int xcd = orig & 7, pos = orig >> 3;
  const int bx = (xcd < r ? xcd * (q + 1) : r * (q + 1) + (xcd - r) * q) + pos;

  const int img = bx / TPI;
  const int sub = bx % TPI;
  const int tY0 = (sub % TILES_Y) * TY;
  const int blkco = sub / TILES_Y;

  const int tid = threadIdx.x;
  const int lane = tid & 63;
  const int lx = lane & 15, kg = lane >> 4;
  const int w = tid >> 6;
  const int pxg = w % NPXG, cog = w / NPXG;

  f32x4 acc[4][4];
  #pragma unroll
  for (int i = 0; i < 4; ++i)
    #pragma unroll
    for (int j = 0; j < 4; ++j) acc[i][j] = (f32x4){0.f, 0.f, 0.f, 0.f};

  for (int cb = 0; cb < NCB; ++cb) {
    if (cb) __syncthreads();
    for (int t2 = tid; t2 < PXT * 8; t2 += 512) {
      int px = t2 >> 3, c = t2 & 7;
      int ry = px / PXW, rx = px - ry * PXW;
      int gy = tY0 + ry - 1, gx = rx - 1;
      float4 v = (float4){0.f, 0.f, 0.f, 0.f};
      if (gy >= 0 && gy < H && gx >= 0 && gx < H) {
        int coff = (c < 4) ? (cb * 32 + c * 8) : (CI + cb * 32 + (c - 4) * 8);
        v = *(const float4*)(actIn + ((long)img * H * H + gy * H + gx) * PIX_IN + coff);
      }
      *(float4*)(smem + c * PLSTR + px * 8) = v;
    }
    __syncthreads();

    for (int s = 0; s < 9; ++s) {
      const int ky = s / 3, kx = s - 3 * (s / 3);
      const long ub = ((long)(s * NCB + cb) * NF + blkco * (COB / 16) + cog * 4) * 1024
                      + lane * 8;
      short8 bh[4], bl[4];
      #pragma unroll
      for (int nf = 0; nf < 4; ++nf) {
        bh[nf] = *(const short8*)(wPk + ub + nf * 1024);
        bl[nf] = *(const short8*)(wPk + ub + nf * 1024 + 512);
      }
      #pragma unroll
      for (int mf = 0; mf < 4; ++mf) {
        const int yoff = (FRX == 2) ? (mf >> 1) : mf;
        const int xb = (FRX == 2) ? ((mf & 1) * 16) : 0;
        const int y = pxg * ROWS_PG + yoff;
        const int pxa = (y + ky) * PXW + xb + kx + lx;
        short8 ah = *(const short8*)(smem + kg * PLSTR + pxa * 8);
        short8 al = *(const short8*)(smem + (kg + 4) * PLSTR + pxa * 8);
        #pragma unroll
        for (int nf = 0; nf < 4; ++nf)
          acc[mf][nf] = __builtin_amdgcn_mfma_f32_16x16x32_bf16(ah, bh[nf], acc[mf][nf], 0, 0, 0);
        #pragma unroll
        for (int nf = 0; nf < 4; ++nf)
          acc[mf][nf] = __builtin_amdgcn_mfma_f32_16x16x32_bf16(ah, bl[nf], acc[mf][nf], 0, 0, 0);
        #pragma unroll
        for (int nf = 0; nf < 4; ++nf)
          acc[mf][nf] = __builtin_amdgcn_mfma_f32_16x16x32_bf16(al, bh[nf], acc[mf][nf], 0, 0, 0);
      }
    }
  }
  __syncthreads();

  float Ar[4], Cr[4];
  #pragma unroll
  for (int nf = 0; nf < 4; ++nf) {
    int co = blkco * COB + cog * 64 + nf * 16 + lx;
    Ar[nf] = Ap[co]; Cr[nf] = Cp[co];
  }

  if (MODE == 0) {
    unsigned short* outA = (unsigned short*)outP;
    unsigned short* slice = smem + w * 2048;
    #pragma unroll
    for (int mf = 0; mf < 4; ++mf) {
      int y = tY0 + pxg * ROWS_PG + mf;
      #pragma unroll
      for (int rr = 0; rr < 4; ++rr) {
        int x = 4 * kg + rr;
        #pragma unroll
        for (int nf = 0; nf < 4; ++nf) {
          float vv = fmaxf(acc[mf][nf][rr] * Ar[nf] + Cr[nf], 0.f);
          unsigned short h = f2bf(vv);
          unsigned short l = f2bf(vv - bf2f(h));
          slice[(x * 2 + 0) * 64 + nf * 16 + lx] = h;
          slice[(x * 2 + 1) * 64 + nf * 16 + lx] = l;
        }
      }
      #pragma unroll
      for (int v = 0; v < 4; ++v) {
        int hoff = lane * 8 + v * 512;
        int x2 = hoff >> 7, rem = hoff & 127;
        int seg = rem >> 6, inner = rem & 63;
        short8 d = *(const short8*)(slice + hoff);
        *(short8*)(outA + ((long)img * 256 + y * 16 + x2) * (2 * CO)
                   + seg * CO + blkco * COB + cog * 64 + inner) = d;
      }
    }
  } else {
    float psum[4] = {0.f, 0.f, 0.f, 0.f};
    #pragma unroll
    for (int nf = 0; nf < 4; ++nf) {
      #pragma unroll
      for (int mfp = 0; mfp < 2; ++mfp) {
        #pragma unroll
        for (int rp = 0; rp < 2; ++rp) {
          float v = fmaxf(fmaxf(acc[2 * mfp][nf][2 * rp], acc[2 * mfp][nf][2 * rp + 1]),
                          fmaxf(acc[2 * mfp + 1][nf][2 * rp], acc[2 * mfp + 1][nf][2 * rp + 1]));
          psum[nf] += fmaxf(v * Ar[nf] + Cr[nf], 0.f);
        }
      }
    }
    #pragma unroll
    for (int nf = 0; nf < 4; ++nf) {
      psum[nf] += __shfl_xor(psum[nf], 16);
      psum[nf] += __shfl_xor(psum[nf], 32);
    }
    __syncthreads();
    float* sR = (float*)smem;
    if (kg == 0) {
      #pragma unroll
      for (int nf = 0; nf < 4; ++nf) sR[w * 64 + nf * 16 + lx] = psum[nf];
    }
    __syncthreads();
    if (tid < COB) {
      int ct = tid >> 6, ci_ = tid & 63;
      float s = 0.f;
      #pragma unroll
      for (int p = 0; p < NPXG; ++p) s += sR[(ct * NPXG + p) * 64 + ci_];
      ((float*)outP)[(long)img * 256 + blkco * COB + tid] = s * (1.f / 64.f);
    }
  }
}

// ---------------------------------------------------------------------------
// conv4 v5: wave = 64px x 128co (acc[4][8]), COB=256 -> 1 block/img.
// Halves per-CU LDS A-fragment reads vs convmf4 (A-frag reuse across 8 nf).
// Same wPk format; same per-element accumulation order (cb -> s -> hh,hl,lh)
// -> bit-identical feats. (512,1): 256-VGPR cap (needs ~220).
__global__ __launch_bounds__(512, 1) void convmf5_kernel(
    const unsigned short* __restrict__ actIn, const unsigned short* __restrict__ wPk,
    const float* __restrict__ Ap, const float* __restrict__ Cp,
    float* __restrict__ feats)
{
  constexpr int CI = 128, CO = 256, H = 16;
  constexpr int NCB = 4, NF = 16;
  constexpr int PXW = 18, PXT = 324;
  constexpr int PLSTR = PXT * 8 + 8;
  constexpr int PIX_IN = 2 * CI;
  __shared__ alignas(16) unsigned short smem[8 * PLSTR];

  const int nwg = gridDim.x;
  const int orig = blockIdx.x;
  const int q = nwg >> 3, r = nwg & 7;
  const int xcd = orig & 7, pos = orig >> 3;
  const int img = (xcd < r ? xcd * (q + 1) : r * (q + 1) + (xcd - r) * q) + pos;

  const int tid = threadIdx.x;
  const int lane = tid & 63;
  const int lx = lane & 15, kg = lane >> 4;
  const int w = tid >> 6;
  const int pxg = w >> 1;        // 0..3 : rows pxg*4 .. pxg*4+3
  const int cog = w & 1;         // 0..1 : co cog*128 .. +127

  f32x4 acc[4][8];
  #pragma unroll
  for (int i = 0; i < 4; ++i)
    #pragma unroll
    for (int j = 0; j < 8; ++j) acc[i][j] = (f32x4){0.f, 0.f, 0.f, 0.f};

  for (int cb = 0; cb < NCB; ++cb) {
    if (cb) __syncthreads();
    for (int t2 = tid; t2 < PXT * 8; t2 += 512) {
      int px = t2 >> 3, c = t2 & 7;
      int ry = px / PXW, rx = px - ry * PXW;
      int gy = ry - 1, gx = rx - 1;
      float4 v = (float4){0.f, 0.f, 0.f, 0.f};
      if (gy >= 0 && gy < H && gx >= 0 && gx < H) {
        int coff = (c < 4) ? (cb * 32 + c * 8) : (CI + cb * 32 + (c - 4) * 8);
        v = *(const float4*)(actIn + ((long)img * H * H + gy * H + gx) * PIX_IN + coff);
      }
      *(float4*)(smem + c * PLSTR + px * 8) = v;
    }
    __syncthreads();

    for (int s = 0; s < 9; ++s) {
      const int ky = s / 3, kx = s - 3 * (s / 3);
      // A fragments for all 4 rows of this px-group (reused across 8 nf)
      short8 ah[4], al[4];
      #pragma unroll
      for (int mf = 0; mf < 4; ++mf) {
        const int pxa = (pxg * 4 + mf + ky) * PXW + kx + lx;
        ah[mf] = *(const short8*)(smem + kg * PLSTR + pxa * 8);
        al[mf] = *(const short8*)(smem + (kg + 4) * PLSTR + pxa * 8);
      }
      const long ub = ((long)(s * NCB + cb) * NF + cog * 8) * 1024 + lane * 8;
      {  // nf chunk 0: acc[mf][0..3]
        short8 bh[4], bl[4];
        #pragma unroll
        for (int nf = 0; nf < 4; ++nf) {
          bh[nf] = *(const short8*)(wPk + ub + nf * 1024);
          bl[nf] = *(const short8*)(wPk + ub + nf * 1024 + 512);
        }
        #pragma unroll
        for (int mf = 0; mf < 4; ++mf) {
          #pragma unroll
          for (int nf = 0; nf < 4; ++nf)
            acc[mf][nf] = __builtin_amdgcn_mfma_f32_16x16x32_bf16(ah[mf], bh[nf], acc[mf][nf], 0, 0, 0);
          #pragma unroll
          for (int nf = 0; nf < 4; ++nf)
            acc[mf][nf] = __builtin_amdgcn_mfma_f32_16x16x32_bf16(ah[mf], bl[nf], acc[mf][nf], 0, 0, 0);
          #pragma unroll
          for (int nf = 0; nf < 4; ++nf)
            acc[mf][nf] = __builtin_amdgcn_mfma_f32_16x16x32_bf16(al[mf], bh[nf], acc[mf][nf], 0, 0, 0);
        }
      }
      {  // nf chunk 1: acc[mf][4..7]
        short8 bh[4], bl[4];
        #pragma unroll
        for (int nf = 0; nf < 4; ++nf) {
          bh[nf] = *(const short8*)(wPk + ub + (4 + nf) * 1024);
          bl[nf] = *(const short8*)(wPk + ub + (4 + nf) * 1024 + 512);
        }
        #pragma unroll
        for (int mf = 0; mf < 4; ++mf) {
          #pragma unroll
          for (int nf = 0; nf < 4; ++nf)
            acc[mf][4 + nf] = __builtin_amdgcn_mfma_f32_16x16x32_bf16(ah[mf], bh[nf], acc[mf][4 + nf], 0, 0, 0);
          #pragma unroll
          for (int nf = 0; nf < 4; ++nf)
            acc[mf][4 + nf] = __builtin_amdgcn_mfma_f32_16x16x32_bf16(ah[mf], bl[nf], acc[mf][4 + nf], 0, 0, 0);
          #pragma unroll
          for (int nf = 0; nf < 4; ++nf)
            acc[mf][4 + nf] = __builtin_amdgcn_mfma_f32_16x16x32_bf16(al[mf], bh[nf], acc[mf][4 + nf], 0, 0, 0);
        }
      }
    }
  }
  __syncthreads();

  // epilogue: 2x2 maxpool + BN/ReLU + global average -> feats
  // acc[mf][j] reg rr: pixel (y = pxg*4+mf, x = 4*kg+rr), co = (cog*8+j)*16+lx
  float psum[8];
  #pragma unroll
  for (int j = 0; j < 8; ++j) psum[j] = 0.f;
  #pragma unroll
  for (int j = 0; j < 8; ++j) {
    int co = (cog * 8 + j) * 16 + lx;
    float Ar = Ap[co], Cr = Cp[co];
    #pragma unroll
    for (int u = 0; u < 2; ++u) {       // y-pairs: (mf 2u, 2u+1)
      #pragma unroll
      for (int v = 0; v < 2; ++v) {     // x-pairs: regs (2v, 2v+1)
        float vm = fmaxf(fmaxf(acc[2 * u][j][2 * v], acc[2 * u][j][2 * v + 1]),
                         fmaxf(acc[2 * u + 1][j][2 * v], acc[2 * u + 1][j][2 * v + 1]));
        psum[j] += fmaxf(vm * Ar + Cr, 0.f);
      }
    }
  }
  #pragma unroll
  for (int j = 0; j < 8; ++j) {
    psum[j] += __shfl_xor(psum[j], 16);
    psum[j] += __shfl_xor(psum[j], 32);
  }
  float* sR = (float*)smem;
  if (kg == 0) {
    #pragma unroll
    for (int j = 0; j < 8; ++j) sR[w * 128 + j * 16 + lx] = psum[j];
  }
  __syncthreads();
  if (tid < 256) {
    int cogT = tid >> 7, cl = tid & 127;
    float s = 0.f;
    #pragma unroll
    for (int p = 0; p < 4; ++p) s += sR[(p * 2 + cogT) * 128 + cl];
    feats[(long)img * 256 + tid] = s * (1.f / 64.f);
  }
}

// ---------------------------------------------------------------------------
// heads / sort / routing / combine (unchanged)
__global__ __launch_bounds__(256) void heads2_kernel(
    const float* __restrict__ feats, const float* __restrict__ gw1,
    const float* __restrict__ gb1, const float* __restrict__ gw2,
    const float* __restrict__ gb2, const float* __restrict__ clsw,
    const float* __restrict__ clsb, const float* __restrict__ usage,
    float* __restrict__ logits_e, float* __restrict__ rs_out)
{
  __shared__ float sF[64 * 257];
  __shared__ float sLg[4 * 64 * 10];
  __shared__ float sRed[4 * 64];
  const int tid = threadIdx.x;
  const int b0 = blockIdx.x * 64;
  const int e  = blockIdx.y;

  for (int idx = tid; idx < 64 * 64; idx += 256) {
    int t = idx >> 6, dg = idx & 63;
    float4 v = ((const float4*)(feats + (long)(b0 + t) * 256))[dg];
    float* p = sF + t * 257 + dg * 4;
    p[0] = v.x; p[1] = v.y; p[2] = v.z; p[3] = v.w;
  }
  __syncthreads();

  const int t  = tid & 63;
  const int hw = __builtin_amdgcn_readfirstlane(tid >> 6);

  {
    float acc[10];
    #pragma unroll
    for (int c = 0; c < 10; ++c) acc[c] = 0.f;
    const float* fp = sF + t * 257 + hw * 64;
    const float* cw = clsw + (long)e * 2560 + hw * 64;
    for (int dd = 0; dd < 64; ++dd) {
      float f = fp[dd];
      #pragma unroll
      for (int c = 0; c < 10; ++c) acc[c] += f * cw[c * 256 + dd];
    }
    #pragma unroll
    for (int c = 0; c < 10; ++c) sLg[(hw * 64 + t) * 10 + c] = acc[c];
  }
  {
    float gacc[32];
    #pragma unroll
    for (int j = 0; j < 32; ++j) gacc[j] = 0.f;
    const float* wb = gw1 + ((long)e * 256) * 128 + hw * 32;
    const float* fp = sF + t * 257;
    for (int d = 0; d < 256; ++d) {
      float f = fp[d];
      const float4* w4 = (const float4*)(wb + (long)d * 128);
      #pragma unroll
      for (int qq = 0; qq < 8; ++qq) {
        float4 wv = w4[qq];
        gacc[4 * qq + 0] += f * wv.x; gacc[4 * qq + 1] += f * wv.y;
        gacc[4 * qq + 2] += f * wv.z; gacc[4 * qq + 3] += f * wv.w;
      }
    }
    float s = 0.f;
    const float* b1 = gb1 + e * 128 + hw * 32;
    const float* w2 = gw2 + e * 128 + hw * 32;
    #pragma unroll
    for (int j = 0; j < 32; ++j) s += fmaxf(gacc[j] + b1[j], 0.f) * w2[j];
    sRed[hw * 64 + t] = s;
  }
  __syncthreads();

  if (tid < 64) {
    float es = (sRed[t] + sRed[64 + t] + sRed[128 + t] + sRed[192 + t] + gb2[e]) * 0.5f;
    float lg[10];
    #pragma unroll
    for (int c = 0; c < 10; ++c)
      lg[c] = sLg[t * 10 + c] + sLg[(64 + t) * 10 + c]
            + sLg[(128 + t) * 10 + c] + sLg[(192 + t) * 10 + c] + clsb[e * 10 + c];
    float mx = lg[0];
    #pragma unroll
    for (int c = 1; c < 10; ++c) mx = fmaxf(mx, lg[c]);
    float S = 0.f, ps[10];
    #pragma unroll
    for (int c = 0; c < 10; ++c) { ps[c] = expf(lg[c] - mx); S += ps[c]; }
    float inv = 1.f / S, ent = 0.f;
    #pragma unroll
    for (int c = 0; c < 10; ++c) { float p = ps[c] * inv; ent -= p * logf(fmaxf(p, 1e-12f)); }
    float rsv = 0.6f * es + 0.4f * (-ent) - 2.0f * usage[e];
    rs_out[(long)(b0 + t) * 16 + e] = rsv;
    #pragma unroll
    for (int c = 0; c < 10; ++c)
      logits_e[((long)(b0 + t) * 16 + e) * 10 + c] = lg[c];
  }
}

__global__ __launch_bounds__(1024) void sort_kernel(
    const float* __restrict__ rs, unsigned* __restrict__ sortedIdx)
{
  __shared__ unsigned long long sk[2048];
  const int e = blockIdx.x;
  const unsigned tid = threadIdx.x;
  for (int i = tid; i < 2048; i += 1024) {
    float f = rs[(long)i * 16 + e];
    unsigned u = __float_as_uint(f);
    u ^= (u >> 31) ? 0xFFFFFFFFu : 0x80000000u;
    sk[i] = ((unsigned long long)(~u) << 32) | (unsigned)i;
  }
  for (unsigned k = 2; k <= 2048; k <<= 1) {
    for (unsigned j = k >> 1; j > 0; j >>= 1) {
      __syncthreads();
      unsigned i = ((tid & ~(j - 1)) << 1) | (tid & (j - 1));
      unsigned p = i | j;
      bool asc = ((i & k) == 0);
      unsigned long long a = sk[i], b = sk[p];
      if ((a > b) == asc) { sk[i] = b; sk[p] = a; }
    }
  }
  __syncthreads();
  for (int i = tid; i < 2048; i += 1024)
    sortedIdx[(long)e * 2048 + i] = (unsigned)(sk[i] & 0xFFFFFFFFull);
}

__global__ __launch_bounds__(64) void routing2_kernel(
    const unsigned* __restrict__ sortedIdx, const float* __restrict__ rs,
    unsigned* __restrict__ dmaskOut)
{
  __shared__ unsigned char sAvail[2048];
  __shared__ unsigned sDm[2048];
  __shared__ int sLoads[16];
  const int lane = threadIdx.x;
  for (int i = lane; i < 2048; i += 64) { sAvail[i] = 1; sDm[i] = 0; }
  if (lane < 16) sLoads[lane] = 0;
  __syncthreads();

  int vc = 2048;
  for (int it = 0; it < 3; ++it) {
    for (int j = 0; j < 16; ++j) {
      int lj = sLoads[j];
      int rc = 256 - lj; if (rc < 0) rc = 0;
      int ntc = 0;
      if (rc > 0 && vc > 0) {
        int a = rc < vc ? rc : vc;
        int b2 = vc < 102 ? vc : 102;
        ntc = a > b2 ? a : b2;
      }
      if (ntc > 0) {
        const unsigned* se = sortedIdx + (long)j * 2048;
        int taken = 0;
        for (int base = 0; base < 2048; base += 64) {
          if (taken >= ntc) break;
          unsigned tok = se[base + lane];
          int fl = sAvail[tok] ? 1 : 0;
          unsigned long long bm = __ballot(fl);
          int pre = taken + __popcll(bm & ((1ull << lane) - 1ull));
          if (fl && pre < ntc) { sAvail[tok] = 0; sDm[tok] |= (1u << j); }
          taken += (int)__popcll(bm);
          __syncthreads();
        }
        if (lane == 0) sLoads[j] = lj + ntc;
        vc -= ntc;
        __syncthreads();
      }
    }
  }

  if (vc > 0) {
    if (lane == 0) {
      for (int i = 0; i < 2048; ++i) {
        if (!sAvail[i]) continue;
        float s0 = -3.4e38f, s1 = s0, s2 = s0; int e0 = 0, e1 = 0, e2 = 0;
        for (int e = 0; e < 16; ++e) {
          float s = rs[i * 16 + e];
          if (s > s0)      { s2 = s1; e2 = e1; s1 = s0; e1 = e0; s0 = s; e0 = e; }
          else if (s > s1) { s2 = s1; e2 = e1; s1 = s;  e1 = e; }
          else if (s > s2) { s2 = s;  e2 = e; }
        }
        int best = e0, bl = sLoads[e0];
        if (sLoads[e1] < bl) { best = e1; bl = sLoads[e1]; }
        if (sLoads[e2] < bl) { best = e2; bl = sLoads[e2]; }
        sDm[i] |= (1u << best);
        sLoads[best] += 1;
      }
    }
    __syncthreads();
  }

  for (int i = lane; i < 2048; i += 64) dmaskOut[i] = sDm[i];
}

__global__ __launch_bounds__(256) void combine_kernel(
    const unsigned* __restrict__ dmask, const float* __restrict__ rs,
    const float* __restrict__ L, float* __restrict__ out, float* __restrict__ Dout)
{
  int i = blockIdx.x * 256 + threadIdx.x;
  if (i >= 2048) return;
  unsigned dm = dmask[i];
  float r[16];
  #pragma unroll
  for (int e = 0; e < 16; ++e) r[e] = rs[i * 16 + e];
  float mx = -3.4e38f;
  #pragma unroll
  for (int e = 0; e < 16; ++e) {
    float v = ((dm >> e) & 1u) ? r[e] : 0.0f;
    mx = fmaxf(mx, v);
  }
  float w[16], S = 0.f;
  #pragma unroll
  for (int e = 0; e < 16; ++e) {
    w[e] = ((dm >> e) & 1u) ? expf(r[e] - mx) : 0.0f;
    S += w[e];
  }
  float inv = 1.f / S;
  #pragma unroll
  for (int c = 0; c < 10; ++c) {
    float a = 0.f;
    #pragma unroll
    for (int e = 0; e < 16; ++e) a += w[e] * L[((long)i * 16 + e) * 10 + c];
    out[i * 10 + c] = a * inv;
  }
  #pragma unroll
  for (int e = 0; e < 16; ++e)
    Dout[(long)i * 16 + e] = ((dm >> e) & 1u) ? 1.0f : 0.0f;
}

// ---------------------------------------------------------------------------
extern "C" void kernel_launch(void* const* d_in, const int* in_sizes, int n_in,
                              void* d_out, int out_size, void* d_ws, size_t ws_size,
                              hipStream_t stream)
{
  const float* x    = (const float*)d_in[0];
  const float* cw1  = (const float*)d_in[1];
  const float* cb1  = (const float*)d_in[2];
  const float* g1   = (const float*)d_in[3];
  const float* be1  = (const float*)d_in[4];
  const float* m1   = (const float*)d_in[5];
  const float* v1   = (const float*)d_in[6];
  const float* cw2  = (const float*)d_in[7];
  const float* cb2  = (const float*)d_in[8];
  const float* g2   = (const float*)d_in[9];
  const float* be2  = (const float*)d_in[10];
  const float* m2   = (const float*)d_in[11];
  const float* v2   = (const float*)d_in[12];
  const float* cw3  = (const float*)d_in[13];
  const float* cb3  = (const float*)d_in[14];
  const float* g3   = (const float*)d_in[15];
  const float* be3  = (const float*)d_in[16];
  const float* m3   = (const float*)d_in[17];
  const float* v3   = (const float*)d_in[18];
  const float* cw4  = (const float*)d_in[19];
  const float* cb4  = (const float*)d_in[20];
  const float* g4   = (const float*)d_in[21];
  const float* be4  = (const float*)d_in[22];
  const float* m4   = (const float*)d_in[23];
  const float* v4   = (const float*)d_in[24];
  const float* gw1  = (const float*)d_in[25];
  const float* gb1  = (const float*)d_in[26];
  const float* gw2  = (const float*)d_in[27];
  const float* gb2  = (const float*)d_in[28];
  const float* clsw = (const float*)d_in[29];
  const float* clsb = (const float*)d_in[30];
  const float* usage = (const float*)d_in[31];

  float* out = (float*)d_out;
  float* ws  = (float*)d_ws;

  float* A1 = ws + 0;   float* C1 = ws + 32;
  float* A2 = ws + 64;  float* C2 = ws + 128;
  float* A3 = ws + 192; float* C3 = ws + 320;
  float* A4 = ws + 448; float* C4 = ws + 704;
  float* feats   = ws + 1024;                       // 2048*256
  float* logitsE = ws + 525312;                     // 2048*16*10
  unsigned* sortedIdx = (unsigned*)(ws + 852992);   // 16*2048
  unsigned* dmask     = (unsigned*)(ws + 885760);   // 2048
  unsigned short* wPk2 = (unsigned short*)(ws + 887808);   // 36 units  * 1024 halves
  unsigned short* wPk3 = (unsigned short*)(ws + 906240);   // 144 units * 1024
  unsigned short* wPk4 = (unsigned short*)(ws + 979968);   // 576 units * 1024
  const long bufBase = 1274880;

  long wsFloats = (long)(ws_size / 4);
  long availF = wsFloats - bufBase;
  long chunkL = availF / 49152;   // per-img: bufA 32768 f + bufB 16384 f
  int chunk = (int)(chunkL < 1 ? 1 : (chunkL > 2048 ? 2048 : chunkL));

  bnprep_kernel<<<1, 256, 0, stream>>>(g1, be1, m1, v1, cb1, A1, C1, 32);
  bnprep_kernel<<<1, 256, 0, stream>>>(g2, be2, m2, v2, cb2, A2, C2, 64);
  bnprep_kernel<<<1, 256, 0, stream>>>(g3, be3, m3, v3, cb3, A3, C3, 128);
  bnprep_kernel<<<1, 256, 0, stream>>>(g4, be4, m4, v4, cb4, A4, C4, 256);
  wprep2_kernel<<<(2304 + 255) / 256, 256, 0, stream>>>(cw2, wPk2, 64, 32);
  wprep2_kernel<<<(9216 + 255) / 256, 256, 0, stream>>>(cw3, wPk3, 128, 64);
  wprep2_kernel<<<(36864 + 255) / 256, 256, 0, stream>>>(cw4, wPk4, 256, 128);

  unsigned short* bufA = (unsigned short*)(ws + bufBase);
  unsigned short* bufB = bufA + (long)chunk * 65536;

  for (int ib = 0; ib < 2048; ib += chunk) {
    int n = 2048 - ib; if (n > chunk) n = chunk;
    // fused conv1+conv2: x -> act2 (act1 stays in LDS)
    conv12_kernel<<<dim3(n * 2), 512, 0, stream>>>(
        x + (long)ib * 3072, cw1, A1, C1, wPk2, A2, C2, bufB);
    // conv3: 16x16, 64->128ch, 1 block/img, plain store -> act3
    convmf4_kernel<16, 64, 128, 128, 16, 16, 0>
        <<<dim3(n), 512, 0, stream>>>(bufB, wPk3, A3, C3, bufA);
    // conv4 v5: 1 block/img, wave = 64px x 128co, pool+avg -> feats
    convmf5_kernel<<<dim3(n), 512, 0, stream>>>(bufA, wPk4, A4, C4,
                                                feats + (long)ib * 256);
  }

  float* rsOut = out + 20480;
  heads2_kernel<<<dim3(32, 16), 256, 0, stream>>>(feats, gw1, gb1, gw2, gb2,
                                                  clsw, clsb, usage, logitsE, rsOut);
  sort_kernel<<<16, 1024, 0, stream>>>(rsOut, sortedIdx);
  routing2_kernel<<<1, 64, 0, stream>>>(sortedIdx, rsOut, dmask);
  combine_kernel<<<8, 256, 0, stream>>>(dmask, rsOut, logitsE, out, out + 53248);
}

// Round 13
// 1211.804 us; speedup vs baseline: 1.1719x; 1.1584x over previous
//
#include <hip/hip_runtime.h>

typedef __attribute__((ext_vector_type(8))) short short8;
typedef __attribute__((ext_vector_type(4))) float f32x4;

__device__ __forceinline__ unsigned short f2bf(float f) {
  unsigned u = __float_as_uint(f);
  unsigned r = (u + 0x7fffu + ((u >> 16) & 1u)) >> 16;
  return (unsigned short)r;
}
__device__ __forceinline__ float bf2f(unsigned short h) {
  return __uint_as_float(((unsigned)h) << 16);
}

// ---------------------------------------------------------------------------
__global__ __launch_bounds__(256) void bnprep_kernel(
    const float* __restrict__ g, const float* __restrict__ be,
    const float* __restrict__ m, const float* __restrict__ v,
    const float* __restrict__ b, float* __restrict__ A, float* __restrict__ C, int n)
{
  int i = blockIdx.x * 256 + threadIdx.x;
  if (i < n) {
    float s = g[i] / sqrtf(v[i] + 1e-5f);
    A[i] = s;
    C[i] = (b[i] - m[i]) * s + be[i];
  }
}

// Pre-pack conv weights into MFMA B-fragment order:
// unit = (s*NCB + cb)*NF + f ; halves addr = unit*1024 + plane*512 + lane*8 + j
__global__ __launch_bounds__(256) void wprep2_kernel(
    const float* __restrict__ w, unsigned short* __restrict__ wPk, int CO, int CI)
{
  int NCB = CI / 32, NF = CO / 16;
  int total = 9 * NCB * NF * 64;
  int idx = blockIdx.x * 256 + threadIdx.x;
  if (idx >= total) return;
  int lane = idx & 63;
  int unit = idx >> 6;
  int f = unit % NF;
  int cb = (unit / NF) % NCB;
  int s = unit / (NF * NCB);
  int co = f * 16 + (lane & 15);
  int ci0 = cb * 32 + (lane >> 4) * 8;
  long base = (long)unit * 1024 + lane * 8;
  #pragma unroll
  for (int j = 0; j < 8; ++j) {
    float v = w[((long)co * CI + ci0 + j) * 9 + s];
    unsigned short h = f2bf(v);
    unsigned short l = f2bf(v - bf2f(h));
    wPk[base + j] = h;
    wPk[base + 512 + j] = l;
  }
}

// ---------------------------------------------------------------------------
// Fused conv1+conv2 (round-10 proven).
__global__ __launch_bounds__(512, 2) void conv12_kernel(
    const float* __restrict__ xin, const float* __restrict__ cw1,
    const float* __restrict__ A1p, const float* __restrict__ C1p,
    const unsigned short* __restrict__ wPk, const float* __restrict__ Ap,
    const float* __restrict__ Cp, unsigned short* __restrict__ outA)
{
  constexpr int TY = 16, TX = 32;
  constexpr int PXW = TX + 2;
  constexpr int PXT = (TY + 2) * PXW;
  constexpr int PLSTR = PXT * 8 + 8;
  constexpr int NF = 4;
  __shared__ alignas(16) unsigned short smem[8 * PLSTR];
  __shared__ alignas(16) float sx[2160];
  __shared__ alignas(16) float sw[864];

  const int nwg = gridDim.x;
  const int orig = blockIdx.x;
  const int q = nwg >> 3, r = nwg & 7;
  const int xcd = orig & 7, pos = orig >> 3;
  const int bx = (xcd < r ? xcd * (q + 1) : r * (q + 1) + (xcd - r) * q) + pos;

  const int img = bx >> 1;
  const int tY0 = (bx & 1) * 16;

  const int tid = threadIdx.x;
  const int lane = tid & 63;
  const int lx = lane & 15, kg = lane >> 4;
  const int w = tid >> 6;

  for (int i = tid; i < 2160; i += 512) {
    int c = i / 720, rem = i - c * 720;
    int yy = rem / 36, xx2 = rem - yy * 36;
    int gy = tY0 + yy - 2, gx = xx2 - 2;
    sx[i] = (gy >= 0 && gy < 32 && gx >= 0 && gx < 32)
            ? xin[(long)img * 3072 + c * 1024 + gy * 32 + gx] : 0.f;
  }
  for (int i = tid; i < 864; i += 512) {
    int co = i & 31, kk = i >> 5;
    sw[kk * 32 + co] = cw1[(long)co * 27 + kk];
  }
  __syncthreads();

  #pragma unroll 1
  for (int p = 0; p < 2; ++p) {
    int px = p * 512 + tid;
    if (px < PXT) {
      int ry = px / PXW, rx = px - ry * PXW;
      int gy = tY0 + ry - 1, gx = rx - 1;
      if (gy >= 0 && gy < 32 && gx >= 0 && gx < 32) {
        #pragma unroll 1
        for (int half = 0; half < 2; ++half) {
          float acc[16];
          #pragma unroll
          for (int j = 0; j < 16; ++j) acc[j] = 0.f;
          #pragma unroll
          for (int c = 0; c < 3; ++c) {
            #pragma unroll
            for (int k = 0; k < 9; ++k) {
              int dy = k / 3, dx = k - 3 * (k / 3);
              float iv = sx[c * 720 + (ry + dy) * 36 + rx + dx];
              const float4* w4 = (const float4*)(sw + (c * 9 + k) * 32 + half * 16);
              #pragma unroll
              for (int q2 = 0; q2 < 4; ++q2) {
                float4 wv = w4[q2];
                acc[4 * q2 + 0] += iv * wv.x; acc[4 * q2 + 1] += iv * wv.y;
                acc[4 * q2 + 2] += iv * wv.z; acc[4 * q2 + 3] += iv * wv.w;
              }
            }
          }
          #pragma unroll
          for (int j2 = 0; j2 < 2; ++j2) {
            short8 hv, lv;
            #pragma unroll
            for (int j = 0; j < 8; ++j) {
              int co = half * 16 + j2 * 8 + j;
              float vv = fmaxf(acc[j2 * 8 + j] * A1p[co] + C1p[co], 0.f);
              unsigned short h = f2bf(vv);
              hv[j] = (short)h;
              lv[j] = (short)f2bf(vv - bf2f(h));
            }
            int plane = half * 2 + j2;
            *(short8*)(smem + plane * PLSTR + px * 8) = hv;
            *(short8*)(smem + (plane + 4) * PLSTR + px * 8) = lv;
          }
        }
      } else {
        short8 zz = {0, 0, 0, 0, 0, 0, 0, 0};
        #pragma unroll
        for (int cc = 0; cc < 8; ++cc)
          *(short8*)(smem + cc * PLSTR + px * 8) = zz;
      }
    }
  }
  __syncthreads();

  f32x4 acc[4][4];
  #pragma unroll
  for (int i = 0; i < 4; ++i)
    #pragma unroll
    for (int j = 0; j < 4; ++j) acc[i][j] = (f32x4){0.f, 0.f, 0.f, 0.f};

  for (int s = 0; s < 9; ++s) {
    const int ky = s / 3, kx = s - 3 * (s / 3);
    const long ub = ((long)(s * NF)) * 1024 + lane * 8;
    short8 bh[4], bl[4];
    #pragma unroll
    for (int nf = 0; nf < 4; ++nf) {
      bh[nf] = *(const short8*)(wPk + ub + nf * 1024);
      bl[nf] = *(const short8*)(wPk + ub + nf * 1024 + 512);
    }
    #pragma unroll
    for (int mf = 0; mf < 4; ++mf) {
      const int yoff = mf >> 1;
      const int xb = (mf & 1) * 16;
      const int y = w * 2 + yoff;
      const int pxa = (y + ky) * PXW + xb + kx + lx;
      short8 ah = *(const short8*)(smem + kg * PLSTR + pxa * 8);
      short8 al = *(const short8*)(smem + (kg + 4) * PLSTR + pxa * 8);
      #pragma unroll
      for (int nf = 0; nf < 4; ++nf)
        acc[mf][nf] = __builtin_amdgcn_mfma_f32_16x16x32_bf16(ah, bh[nf], acc[mf][nf], 0, 0, 0);
      #pragma unroll
      for (int nf = 0; nf < 4; ++nf)
        acc[mf][nf] = __builtin_amdgcn_mfma_f32_16x16x32_bf16(ah, bl[nf], acc[mf][nf], 0, 0, 0);
      #pragma unroll
      for (int nf = 0; nf < 4; ++nf)
        acc[mf][nf] = __builtin_amdgcn_mfma_f32_16x16x32_bf16(al, bh[nf], acc[mf][nf], 0, 0, 0);
    }
  }
  __syncthreads();

  float Ar[4], Cr[4];
  #pragma unroll
  for (int nf = 0; nf < 4; ++nf) {
    int co = nf * 16 + lx;
    Ar[nf] = Ap[co]; Cr[nf] = Cp[co];
  }

  unsigned short* slice = smem + w * 2048;
  const int py = (tY0 >> 1) + w;
  #pragma unroll
  for (int xf = 0; xf < 2; ++xf) {
    #pragma unroll
    for (int rp = 0; rp < 2; ++rp) {
      int ox = xf * 8 + 2 * kg + rp;
      #pragma unroll
      for (int nf = 0; nf < 4; ++nf) {
        float v0 = fmaxf(fmaxf(acc[xf][nf][2 * rp], acc[xf][nf][2 * rp + 1]),
                         fmaxf(acc[xf + 2][nf][2 * rp], acc[xf + 2][nf][2 * rp + 1]));
        float vv = fmaxf(v0 * Ar[nf] + Cr[nf], 0.f);
        unsigned short h = f2bf(vv);
        unsigned short l = f2bf(vv - bf2f(h));
        slice[(ox * 2 + 0) * 64 + nf * 16 + lx] = h;
        slice[(ox * 2 + 1) * 64 + nf * 16 + lx] = l;
      }
    }
  }
  #pragma unroll
  for (int v = 0; v < 4; ++v) {
    int hoff = lane * 8 + v * 512;
    int x2 = hoff >> 7, rem = hoff & 127;
    int seg = rem >> 6, inner = rem & 63;
    short8 d = *(const short8*)(slice + hoff);
    *(short8*)(outA + ((long)img * 256 + py * 16 + x2) * 128 + seg * 64 + inner) = d;
  }
}

// ---------------------------------------------------------------------------
// Fused conv3+conv4: act3 lives entirely in LDS (32 planes x 2056 + zero
// page). Phase 1: conv3 (wave = 2 rows x 128 co, acc3[2][8]) from staged
// act2. Phase 2: act3 split-bf16 write into planes. Phase 3: conv4 with
// convmf5 geometry (wave = 4 rows x 128 co, acc[4][8]) reading act3 directly
// from LDS -- zero restaging; halo handled by per-lane zero-page select.
// Accumulation order matches rounds 8-12 exactly -> bit-identical feats.
__global__ __launch_bounds__(512, 1) void convmf45_kernel(
    const unsigned short* __restrict__ act2,
    const unsigned short* __restrict__ wPk3, const float* __restrict__ A3p,
    const float* __restrict__ C3p,
    const unsigned short* __restrict__ wPk4, const float* __restrict__ A4p,
    const float* __restrict__ C4p, float* __restrict__ feats)
{
  constexpr int PLSTR3 = 2056;          // act3 plane stride (halves)
  constexpr int ZOFF = 32 * PLSTR3;     // zero page offset (65792)
  constexpr int PXW2 = 18, PXT2 = 324;  // act2 staging (halo'd)
  constexpr int PLSTR2 = PXT2 * 8 + 8;  // 2600
  __shared__ alignas(16) unsigned short smem[ZOFF + 64];   // 131,712 B

  const int nwg = gridDim.x;
  const int orig = blockIdx.x;
  const int q = nwg >> 3, r = nwg & 7;
  const int xcd = orig & 7, pos = orig >> 3;
  const int img = (xcd < r ? xcd * (q + 1) : r * (q + 1) + (xcd - r) * q) + pos;

  const int tid = threadIdx.x;
  const int lane = tid & 63;
  const int lx = lane & 15, kg = lane >> 4;
  const int w = tid >> 6;

  if (tid < 8) {
    short8 zz = {0, 0, 0, 0, 0, 0, 0, 0};
    *(short8*)(smem + ZOFF + tid * 8) = zz;
  }

  // ---------------- phase 1: conv3 (64->128), wave = rows 2w..2w+1, 128 co
  f32x4 acc3[2][8];
  #pragma unroll
  for (int i = 0; i < 2; ++i)
    #pragma unroll
    for (int j = 0; j < 8; ++j) acc3[i][j] = (f32x4){0.f, 0.f, 0.f, 0.f};

  for (int cb = 0; cb < 2; ++cb) {
    __syncthreads();
    for (int t2 = tid; t2 < PXT2 * 8; t2 += 512) {
      int px = t2 >> 3, c = t2 & 7;
      int ry = px / PXW2, rx = px - ry * PXW2;
      int gy = ry - 1, gx = rx - 1;
      float4 v = (float4){0.f, 0.f, 0.f, 0.f};
      if (gy >= 0 && gy < 16 && gx >= 0 && gx < 16) {
        int coff = (c < 4) ? (cb * 32 + c * 8) : (64 + cb * 32 + (c - 4) * 8);
        v = *(const float4*)(act2 + ((long)img * 256 + gy * 16 + gx) * 128 + coff);
      }
      *(float4*)(smem + c * PLSTR2 + px * 8) = v;
    }
    __syncthreads();

    for (int s = 0; s < 9; ++s) {
      const int ky = s / 3, kx = s - 3 * (s / 3);
      short8 ah[2], al[2];
      #pragma unroll
      for (int mf = 0; mf < 2; ++mf) {
        const int pxa = (w * 2 + mf + ky) * PXW2 + kx + lx;
        ah[mf] = *(const short8*)(smem + kg * PLSTR2 + pxa * 8);
        al[mf] = *(const short8*)(smem + (kg + 4) * PLSTR2 + pxa * 8);
      }
      const long ub = ((long)(s * 2 + cb) * 8) * 1024 + lane * 8;
      {  // nf chunk 0
        short8 bh[4], bl[4];
        #pragma unroll
        for (int nf = 0; nf < 4; ++nf) {
          bh[nf] = *(const short8*)(wPk3 + ub + nf * 1024);
          bl[nf] = *(const short8*)(wPk3 + ub + nf * 1024 + 512);
        }
        #pragma unroll
        for (int mf = 0; mf < 2; ++mf) {
          #pragma unroll
          for (int nf = 0; nf < 4; ++nf)
            acc3[mf][nf] = __builtin_amdgcn_mfma_f32_16x16x32_bf16(ah[mf], bh[nf], acc3[mf][nf], 0, 0, 0);
          #pragma unroll
          for (int nf = 0; nf < 4; ++nf)
            acc3[mf][nf] = __builtin_amdgcn_mfma_f32_16x16x32_bf16(ah[mf], bl[nf], acc3[mf][nf], 0, 0, 0);
          #pragma unroll
          for (int nf = 0; nf < 4; ++nf)
            acc3[mf][nf] = __builtin_amdgcn_mfma_f32_16x16x32_bf16(al[mf], bh[nf], acc3[mf][nf], 0, 0, 0);
        }
      }
      {  // nf chunk 1
        short8 bh[4], bl[4];
        #pragma unroll
        for (int nf = 0; nf < 4; ++nf) {
          bh[nf] = *(const short8*)(wPk3 + ub + (4 + nf) * 1024);
          bl[nf] = *(const short8*)(wPk3 + ub + (4 + nf) * 1024 + 512);
        }
        #pragma unroll
        for (int mf = 0; mf < 2; ++mf) {
          #pragma unroll
          for (int nf = 0; nf < 4; ++nf)
            acc3[mf][4 + nf] = __builtin_amdgcn_mfma_f32_16x16x32_bf16(ah[mf], bh[nf], acc3[mf][4 + nf], 0, 0, 0);
          #pragma unroll
          for (int nf = 0; nf < 4; ++nf)
            acc3[mf][4 + nf] = __builtin_amdgcn_mfma_f32_16x16x32_bf16(ah[mf], bl[nf], acc3[mf][4 + nf], 0, 0, 0);
          #pragma unroll
          for (int nf = 0; nf < 4; ++nf)
            acc3[mf][4 + nf] = __builtin_amdgcn_mfma_f32_16x16x32_bf16(al[mf], bh[nf], acc3[mf][4 + nf], 0, 0, 0);
        }
      }
    }
  }
  __syncthreads();   // all conv3 reads of staging region complete

  // ---------------- phase 2: BN/ReLU + split-bf16 act3 -> LDS planes
  #pragma unroll
  for (int mf = 0; mf < 2; ++mf) {
    int y = w * 2 + mf;
    #pragma unroll
    for (int rr = 0; rr < 4; ++rr) {
      int px = y * 16 + 4 * kg + rr;
      #pragma unroll
      for (int nf = 0; nf < 8; ++nf) {
        int co = nf * 16 + lx;
        float vv = fmaxf(acc3[mf][nf][rr] * A3p[co] + C3p[co], 0.f);
        unsigned short h = f2bf(vv);
        unsigned short l = f2bf(vv - bf2f(h));
        int plane = co >> 3, j = co & 7;
        smem[plane * PLSTR3 + px * 8 + j] = h;
        smem[(plane + 16) * PLSTR3 + px * 8 + j] = l;
      }
    }
  }
  __syncthreads();

  // ---------------- phase 3: conv4 (128->256), convmf5 geometry, no staging
  const int pxg = w >> 1;        // 0..3 : rows pxg*4 .. pxg*4+3
  const int cog = w & 1;         // 0..1 : co cog*128 .. +127

  f32x4 acc[4][8];
  #pragma unroll
  for (int i = 0; i < 4; ++i)
    #pragma unroll
    for (int j = 0; j < 8; ++j) acc[i][j] = (f32x4){0.f, 0.f, 0.f, 0.f};

  for (int cb = 0; cb < 4; ++cb) {
    for (int s = 0; s < 9; ++s) {
      const int ky = s / 3, kx = s - 3 * (s / 3);
      short8 ah[4], al[4];
      #pragma unroll
      for (int mf = 0; mf < 4; ++mf) {
        int gy = pxg * 4 + mf + ky - 1;
        int gxx = lx + kx - 1;
        bool ok = (gy >= 0) && (gy < 16) && (gxx >= 0) && (gxx < 16);
        int pxo = (gy * 16 + gxx) * 8;
        int offH = ok ? ((cb * 4 + kg) * PLSTR3 + pxo) : ZOFF;
        int offL = ok ? ((16 + cb * 4 + kg) * PLSTR3 + pxo) : ZOFF;
        ah[mf] = *(const short8*)(smem + offH);
        al[mf] = *(const short8*)(smem + offL);
      }
      const long ub = ((long)(s * 4 + cb) * 16 + cog * 8) * 1024 + lane * 8;
      {  // nf chunk 0: acc[mf][0..3]
        short8 bh[4], bl[4];
        #pragma unroll
        for (int nf = 0; nf < 4; ++nf) {
          bh[nf] = *(const short8*)(wPk4 + ub + nf * 1024);
          bl[nf] = *(const short8*)(wPk4 + ub + nf * 1024 + 512);
        }
        #pragma unroll
        for (int mf = 0; mf < 4; ++mf) {
          #pragma unroll
          for (int nf = 0; nf < 4; ++nf)
            acc[mf][nf] = __builtin_amdgcn_mfma_f32_16x16x32_bf16(ah[mf], bh[nf], acc[mf][nf], 0, 0, 0);
          #pragma unroll
          for (int nf = 0; nf < 4; ++nf)
            acc[mf][nf] = __builtin_amdgcn_mfma_f32_16x16x32_bf16(ah[mf], bl[nf], acc[mf][nf], 0, 0, 0);
          #pragma unroll
          for (int nf = 0; nf < 4; ++nf)
            acc[mf][nf] = __builtin_amdgcn_mfma_f32_16x16x32_bf16(al[mf], bh[nf], acc[mf][nf], 0, 0, 0);
        }
      }
      {  // nf chunk 1: acc[mf][4..7]
        short8 bh[4], bl[4];
        #pragma unroll
        for (int nf = 0; nf < 4; ++nf) {
          bh[nf] = *(const short8*)(wPk4 + ub + (4 + nf) * 1024);
          bl[nf] = *(const short8*)(wPk4 + ub + (4 + nf) * 1024 + 512);
        }
        #pragma unroll
        for (int mf = 0; mf < 4; ++mf) {
          #pragma unroll
          for (int nf = 0; nf < 4; ++nf)
            acc[mf][4 + nf] = __builtin_amdgcn_mfma_f32_16x16x32_bf16(ah[mf], bh[nf], acc[mf][4 + nf], 0, 0, 0);
          #pragma unroll
          for (int nf = 0; nf < 4; ++nf)
            acc[mf][4 + nf] = __builtin_amdgcn_mfma_f32_16x16x32_bf16(ah[mf], bl[nf], acc[mf][4 + nf], 0, 0, 0);
          #pragma unroll
          for (int nf = 0; nf < 4; ++nf)
            acc[mf][4 + nf] = __builtin_amdgcn_mfma_f32_16x16x32_bf16(al[mf], bh[nf], acc[mf][4 + nf], 0, 0, 0);
        }
      }
    }
  }
  __syncthreads();   // all conv4 LDS reads complete before sR reuse

  // epilogue: 2x2 maxpool + BN/ReLU + global average -> feats (convmf5)
  float psum[8];
  #pragma unroll
  for (int j = 0; j < 8; ++j) psum[j] = 0.f;
  #pragma unroll
  for (int j = 0; j < 8; ++j) {
    int co = (cog * 8 + j) * 16 + lx;
    float Ar = A4p[co], Cr = C4p[co];
    #pragma unroll
    for (int u = 0; u < 2; ++u) {
      #pragma unroll
      for (int v = 0; v < 2; ++v) {
        float vm = fmaxf(fmaxf(acc[2 * u][j][2 * v], acc[2 * u][j][2 * v + 1]),
                         fmaxf(acc[2 * u + 1][j][2 * v], acc[2 * u + 1][j][2 * v + 1]));
        psum[j] += fmaxf(vm * Ar + Cr, 0.f);
      }
    }
  }
  #pragma unroll
  for (int j = 0; j < 8; ++j) {
    psum[j] += __shfl_xor(psum[j], 16);
    psum[j] += __shfl_xor(psum[j], 32);
  }
  float* sR = (float*)smem;
  if (kg == 0) {
    #pragma unroll
    for (int j = 0; j < 8; ++j) sR[w * 128 + j * 16 + lx] = psum[j];
  }
  __syncthreads();
  if (tid < 256) {
    int cogT = tid >> 7, cl = tid & 127;
    float s = 0.f;
    #pragma unroll
    for (int p = 0; p < 4; ++p) s += sR[(p * 2 + cogT) * 128 + cl];
    feats[(long)img * 256 + tid] = s * (1.f / 64.f);
  }
}

// ---------------------------------------------------------------------------
// heads / sort / routing / combine (unchanged)
__global__ __launch_bounds__(256) void heads2_kernel(
    const float* __restrict__ feats, const float* __restrict__ gw1,
    const float* __restrict__ gb1, const float* __restrict__ gw2,
    const float* __restrict__ gb2, const float* __restrict__ clsw,
    const float* __restrict__ clsb, const float* __restrict__ usage,
    float* __restrict__ logits_e, float* __restrict__ rs_out)
{
  __shared__ float sF[64 * 257];
  __shared__ float sLg[4 * 64 * 10];
  __shared__ float sRed[4 * 64];
  const int tid = threadIdx.x;
  const int b0 = blockIdx.x * 64;
  const int e  = blockIdx.y;

  for (int idx = tid; idx < 64 * 64; idx += 256) {
    int t = idx >> 6, dg = idx & 63;
    float4 v = ((const float4*)(feats + (long)(b0 + t) * 256))[dg];
    float* p = sF + t * 257 + dg * 4;
    p[0] = v.x; p[1] = v.y; p[2] = v.z; p[3] = v.w;
  }
  __syncthreads();

  const int t  = tid & 63;
  const int hw = __builtin_amdgcn_readfirstlane(tid >> 6);

  {
    float acc[10];
    #pragma unroll
    for (int c = 0; c < 10; ++c) acc[c] = 0.f;
    const float* fp = sF + t * 257 + hw * 64;
    const float* cw = clsw + (long)e * 2560 + hw * 64;
    for (int dd = 0; dd < 64; ++dd) {
      float f = fp[dd];
      #pragma unroll
      for (int c = 0; c < 10; ++c) acc[c] += f * cw[c * 256 + dd];
    }
    #pragma unroll
    for (int c = 0; c < 10; ++c) sLg[(hw * 64 + t) * 10 + c] = acc[c];
  }
  {
    float gacc[32];
    #pragma unroll
    for (int j = 0; j < 32; ++j) gacc[j] = 0.f;
    const float* wb = gw1 + ((long)e * 256) * 128 + hw * 32;
    const float* fp = sF + t * 257;
    for (int d = 0; d < 256; ++d) {
      float f = fp[d];
      const float4* w4 = (const float4*)(wb + (long)d * 128);
      #pragma unroll
      for (int qq = 0; qq < 8; ++qq) {
        float4 wv = w4[qq];
        gacc[4 * qq + 0] += f * wv.x; gacc[4 * qq + 1] += f * wv.y;
        gacc[4 * qq + 2] += f * wv.z; gacc[4 * qq + 3] += f * wv.w;
      }
    }
    float s = 0.f;
    const float* b1 = gb1 + e * 128 + hw * 32;
    const float* w2 = gw2 + e * 128 + hw * 32;
    #pragma unroll
    for (int j = 0; j < 32; ++j) s += fmaxf(gacc[j] + b1[j], 0.f) * w2[j];
    sRed[hw * 64 + t] = s;
  }
  __syncthreads();

  if (tid < 64) {
    float es = (sRed[t] + sRed[64 + t] + sRed[128 + t] + sRed[192 + t] + gb2[e]) * 0.5f;
    float lg[10];
    #pragma unroll
    for (int c = 0; c < 10; ++c)
      lg[c] = sLg[t * 10 + c] + sLg[(64 + t) * 10 + c]
            + sLg[(128 + t) * 10 + c] + sLg[(192 + t) * 10 + c] + clsb[e * 10 + c];
    float mx = lg[0];
    #pragma unroll
    for (int c = 1; c < 10; ++c) mx = fmaxf(mx, lg[c]);
    float S = 0.f, ps[10];
    #pragma unroll
    for (int c = 0; c < 10; ++c) { ps[c] = expf(lg[c] - mx); S += ps[c]; }
    float inv = 1.f / S, ent = 0.f;
    #pragma unroll
    for (int c = 0; c < 10; ++c) { float p = ps[c] * inv; ent -= p * logf(fmaxf(p, 1e-12f)); }
    float rsv = 0.6f * es + 0.4f * (-ent) - 2.0f * usage[e];
    rs_out[(long)(b0 + t) * 16 + e] = rsv;
    #pragma unroll
    for (int c = 0; c < 10; ++c)
      logits_e[((long)(b0 + t) * 16 + e) * 10 + c] = lg[c];
  }
}

__global__ __launch_bounds__(1024) void sort_kernel(
    const float* __restrict__ rs, unsigned* __restrict__ sortedIdx)
{
  __shared__ unsigned long long sk[2048];
  const int e = blockIdx.x;
  const unsigned tid = threadIdx.x;
  for (int i = tid; i < 2048; i += 1024) {
    float f = rs[(long)i * 16 + e];
    unsigned u = __float_as_uint(f);
    u ^= (u >> 31) ? 0xFFFFFFFFu : 0x80000000u;
    sk[i] = ((unsigned long long)(~u) << 32) | (unsigned)i;
  }
  for (unsigned k = 2; k <= 2048; k <<= 1) {
    for (unsigned j = k >> 1; j > 0; j >>= 1) {
      __syncthreads();
      unsigned i = ((tid & ~(j - 1)) << 1) | (tid & (j - 1));
      unsigned p = i | j;
      bool asc = ((i & k) == 0);
      unsigned long long a = sk[i], b = sk[p];
      if ((a > b) == asc) { sk[i] = b; sk[p] = a; }
    }
  }
  __syncthreads();
  for (int i = tid; i < 2048; i += 1024)
    sortedIdx[(long)e * 2048 + i] = (unsigned)(sk[i] & 0xFFFFFFFFull);
}

__global__ __launch_bounds__(64) void routing2_kernel(
    const unsigned* __restrict__ sortedIdx, const float* __restrict__ rs,
    unsigned* __restrict__ dmaskOut)
{
  __shared__ unsigned char sAvail[2048];
  __shared__ unsigned sDm[2048];
  __shared__ int sLoads[16];
  const int lane = threadIdx.x;
  for (int i = lane; i < 2048; i += 64) { sAvail[i] = 1; sDm[i] = 0; }
  if (lane < 16) sLoads[lane] = 0;
  __syncthreads();

  int vc = 2048;
  for (int it = 0; it < 3; ++it) {
    for (int j = 0; j < 16; ++j) {
      int lj = sLoads[j];
      int rc = 256 - lj; if (rc < 0) rc = 0;
      int ntc = 0;
      if (rc > 0 && vc > 0) {
        int a = rc < vc ? rc : vc;
        int b2 = vc < 102 ? vc : 102;
        ntc = a > b2 ? a : b2;
      }
      if (ntc > 0) {
        const unsigned* se = sortedIdx + (long)j * 2048;
        int taken = 0;
        for (int base = 0; base < 2048; base += 64) {
          if (taken >= ntc) break;
          unsigned tok = se[base + lane];
          int fl = sAvail[tok] ? 1 : 0;
          unsigned long long bm = __ballot(fl);
          int pre = taken + __popcll(bm & ((1ull << lane) - 1ull));
          if (fl && pre < ntc) { sAvail[tok] = 0; sDm[tok] |= (1u << j); }
          taken += (int)__popcll(bm);
          __syncthreads();
        }
        if (lane == 0) sLoads[j] = lj + ntc;
        vc -= ntc;
        __syncthreads();
      }
    }
  }

  if (vc > 0) {
    if (lane == 0) {
      for (int i = 0; i < 2048; ++i) {
        if (!sAvail[i]) continue;
        float s0 = -3.4e38f, s1 = s0, s2 = s0; int e0 = 0, e1 = 0, e2 = 0;
        for (int e = 0; e < 16; ++e) {
          float s = rs[i * 16 + e];
          if (s > s0)      { s2 = s1; e2 = e1; s1 = s0; e1 = e0; s0 = s; e0 = e; }
          else if (s > s1) { s2 = s1; e2 = e1; s1 = s;  e1 = e; }
          else if (s > s2) { s2 = s;  e2 = e; }
        }
        int best = e0, bl = sLoads[e0];
        if (sLoads[e1] < bl) { best = e1; bl = sLoads[e1]; }
        if (sLoads[e2] < bl) { best = e2; bl = sLoads[e2]; }
        sDm[i] |= (1u << best);
        sLoads[best] += 1;
      }
    }
    __syncthreads();
  }

  for (int i = lane; i < 2048; i += 64) dmaskOut[i] = sDm[i];
}

__global__ __launch_bounds__(256) void combine_kernel(
    const unsigned* __restrict__ dmask, const float* __restrict__ rs,
    const float* __restrict__ L, float* __restrict__ out, float* __restrict__ Dout)
{
  int i = blockIdx.x * 256 + threadIdx.x;
  if (i >= 2048) return;
  unsigned dm = dmask[i];
  float r[16];
  #pragma unroll
  for (int e = 0; e < 16; ++e) r[e] = rs[i * 16 + e];
  float mx = -3.4e38f;
  #pragma unroll
  for (int e = 0; e < 16; ++e) {
    float v = ((dm >> e) & 1u) ? r[e] : 0.0f;
    mx = fmaxf(mx, v);
  }
  float w[16], S = 0.f;
  #pragma unroll
  for (int e = 0; e < 16; ++e) {
    w[e] = ((dm >> e) & 1u) ? expf(r[e] - mx) : 0.0f;
    S += w[e];
  }
  float inv = 1.f / S;
  #pragma unroll
  for (int c = 0; c < 10; ++c) {
    float a = 0.f;
    #pragma unroll
    for (int e = 0; e < 16; ++e) a += w[e] * L[((long)i * 16 + e) * 10 + c];
    out[i * 10 + c] = a * inv;
  }
  #pragma unroll
  for (int e = 0; e < 16; ++e)
    Dout[(long)i * 16 + e] = ((dm >> e) & 1u) ? 1.0f : 0.0f;
}

// ---------------------------------------------------------------------------
extern "C" void kernel_launch(void* const* d_in, const int* in_sizes, int n_in,
                              void* d_out, int out_size, void* d_ws, size_t ws_size,
                              hipStream_t stream)
{
  const float* x    = (const float*)d_in[0];
  const float* cw1  = (const float*)d_in[1];
  const float* cb1  = (const float*)d_in[2];
  const float* g1   = (const float*)d_in[3];
  const float* be1  = (const float*)d_in[4];
  const float* m1   = (const float*)d_in[5];
  const float* v1   = (const float*)d_in[6];
  const float* cw2  = (const float*)d_in[7];
  const float* cb2  = (const float*)d_in[8];
  const float* g2   = (const float*)d_in[9];
  const float* be2  = (const float*)d_in[10];
  const float* m2   = (const float*)d_in[11];
  const float* v2   = (const float*)d_in[12];
  const float* cw3  = (const float*)d_in[13];
  const float* cb3  = (const float*)d_in[14];
  const float* g3   = (const float*)d_in[15];
  const float* be3  = (const float*)d_in[16];
  const float* m3   = (const float*)d_in[17];
  const float* v3   = (const float*)d_in[18];
  const float* cw4  = (const float*)d_in[19];
  const float* cb4  = (const float*)d_in[20];
  const float* g4   = (const float*)d_in[21];
  const float* be4  = (const float*)d_in[22];
  const float* m4   = (const float*)d_in[23];
  const float* v4   = (const float*)d_in[24];
  const float* gw1  = (const float*)d_in[25];
  const float* gb1  = (const float*)d_in[26];
  const float* gw2  = (const float*)d_in[27];
  const float* gb2  = (const float*)d_in[28];
  const float* clsw = (const float*)d_in[29];
  const float* clsb = (const float*)d_in[30];
  const float* usage = (const float*)d_in[31];

  float* out = (float*)d_out;
  float* ws  = (float*)d_ws;

  float* A1 = ws + 0;   float* C1 = ws + 32;
  float* A2 = ws + 64;  float* C2 = ws + 128;
  float* A3 = ws + 192; float* C3 = ws + 320;
  float* A4 = ws + 448; float* C4 = ws + 704;
  float* feats   = ws + 1024;                       // 2048*256
  float* logitsE = ws + 525312;                     // 2048*16*10
  unsigned* sortedIdx = (unsigned*)(ws + 852992);   // 16*2048
  unsigned* dmask     = (unsigned*)(ws + 885760);   // 2048
  unsigned short* wPk2 = (unsigned short*)(ws + 887808);   // 36 units  * 1024 halves
  unsigned short* wPk3 = (unsigned short*)(ws + 906240);   // 144 units * 1024
  unsigned short* wPk4 = (unsigned short*)(ws + 979968);   // 576 units * 1024
  const long bufBase = 1274880;

  long wsFloats = (long)(ws_size / 4);
  long availF = wsFloats - bufBase;
  long chunkL = availF / 16384;   // per-img: act2 only (16384 floats)
  int chunk = (int)(chunkL < 1 ? 1 : (chunkL > 2048 ? 2048 : chunkL));

  bnprep_kernel<<<1, 256, 0, stream>>>(g1, be1, m1, v1, cb1, A1, C1, 32);
  bnprep_kernel<<<1, 256, 0, stream>>>(g2, be2, m2, v2, cb2, A2, C2, 64);
  bnprep_kernel<<<1, 256, 0, stream>>>(g3, be3, m3, v3, cb3, A3, C3, 128);
  bnprep_kernel<<<1, 256, 0, stream>>>(g4, be4, m4, v4, cb4, A4, C4, 256);
  wprep2_kernel<<<(2304 + 255) / 256, 256, 0, stream>>>(cw2, wPk2, 64, 32);
  wprep2_kernel<<<(9216 + 255) / 256, 256, 0, stream>>>(cw3, wPk3, 128, 64);
  wprep2_kernel<<<(36864 + 255) / 256, 256, 0, stream>>>(cw4, wPk4, 256, 128);

  unsigned short* act2buf = (unsigned short*)(ws + bufBase);

  for (int ib = 0; ib < 2048; ib += chunk) {
    int n = 2048 - ib; if (n > chunk) n = chunk;
    // fused conv1+conv2: x -> act2 (act1 stays in LDS)
    conv12_kernel<<<dim3(n * 2), 512, 0, stream>>>(
        x + (long)ib * 3072, cw1, A1, C1, wPk2, A2, C2, act2buf);
    // fused conv3+conv4: act2 -> feats (act3 stays in LDS)
    convmf45_kernel<<<dim3(n), 512, 0, stream>>>(
        act2buf, wPk3, A3, C3, wPk4, A4, C4, feats + (long)ib * 256);
  }

  float* rsOut = out + 20480;
  heads2_kernel<<<dim3(32, 16), 256, 0, stream>>>(feats, gw1, gb1, gw2, gb2,
                                                  clsw, clsb, usage, logitsE, rsOut);
  sort_kernel<<<16, 1024, 0, stream>>>(rsOut, sortedIdx);
  routing2_kernel<<<1, 64, 0, stream>>>(sortedIdx, rsOut, dmask);
  combine_kernel<<<8, 256, 0, stream>>>(dmask, rsOut, logitsE, out, out + 53248);
}

// Round 14
// 1202.550 us; speedup vs baseline: 1.1809x; 1.0077x over previous
//
#include <hip/hip_runtime.h>

typedef __attribute__((ext_vector_type(8))) short short8;
typedef __attribute__((ext_vector_type(4))) float f32x4;

__device__ __forceinline__ unsigned short f2bf(float f) {
  unsigned u = __float_as_uint(f);
  unsigned r = (u + 0x7fffu + ((u >> 16) & 1u)) >> 16;
  return (unsigned short)r;
}
__device__ __forceinline__ float bf2f(unsigned short h) {
  return __uint_as_float(((unsigned)h) << 16);
}

// ---------------------------------------------------------------------------
__global__ __launch_bounds__(256) void bnprep_kernel(
    const float* __restrict__ g, const float* __restrict__ be,
    const float* __restrict__ m, const float* __restrict__ v,
    const float* __restrict__ b, float* __restrict__ A, float* __restrict__ C, int n)
{
  int i = blockIdx.x * 256 + threadIdx.x;
  if (i < n) {
    float s = g[i] / sqrtf(v[i] + 1e-5f);
    A[i] = s;
    C[i] = (b[i] - m[i]) * s + be[i];
  }
}

// Pre-pack conv weights into MFMA B-fragment order:
// unit = (s*NCB + cb)*NF + f ; halves addr = unit*1024 + plane*512 + lane*8 + j
__global__ __launch_bounds__(256) void wprep2_kernel(
    const float* __restrict__ w, unsigned short* __restrict__ wPk, int CO, int CI)
{
  int NCB = CI / 32, NF = CO / 16;
  int total = 9 * NCB * NF * 64;
  int idx = blockIdx.x * 256 + threadIdx.x;
  if (idx >= total) return;
  int lane = idx & 63;
  int unit = idx >> 6;
  int f = unit % NF;
  int cb = (unit / NF) % NCB;
  int s = unit / (NF * NCB);
  int co = f * 16 + (lane & 15);
  int ci0 = cb * 32 + (lane >> 4) * 8;
  long base = (long)unit * 1024 + lane * 8;
  #pragma unroll
  for (int j = 0; j < 8; ++j) {
    float v = w[((long)co * CI + ci0 + j) * 9 + s];
    unsigned short h = f2bf(v);
    unsigned short l = f2bf(v - bf2f(h));
    wPk[base + j] = h;
    wPk[base + 512 + j] = l;
  }
}

// ---------------------------------------------------------------------------
// Fused conv1+conv2 (round-10 proven).
__global__ __launch_bounds__(512, 2) void conv12_kernel(
    const float* __restrict__ xin, const float* __restrict__ cw1,
    const float* __restrict__ A1p, const float* __restrict__ C1p,
    const unsigned short* __restrict__ wPk, const float* __restrict__ Ap,
    const float* __restrict__ Cp, unsigned short* __restrict__ outA)
{
  constexpr int TY = 16, TX = 32;
  constexpr int PXW = TX + 2;
  constexpr int PXT = (TY + 2) * PXW;
  constexpr int PLSTR = PXT * 8 + 8;
  constexpr int NF = 4;
  __shared__ alignas(16) unsigned short smem[8 * PLSTR];
  __shared__ alignas(16) float sx[2160];
  __shared__ alignas(16) float sw[864];

  const int nwg = gridDim.x;
  const int orig = blockIdx.x;
  const int q = nwg >> 3, r = nwg & 7;
  const int xcd = orig & 7, pos = orig >> 3;
  const int bx = (xcd < r ? xcd * (q + 1) : r * (q + 1) + (xcd - r) * q) + pos;

  const int img = bx >> 1;
  const int tY0 = (bx & 1) * 16;

  const int tid = threadIdx.x;
  const int lane = tid & 63;
  const int lx = lane & 15, kg = lane >> 4;
  const int w = tid >> 6;

  for (int i = tid; i < 2160; i += 512) {
    int c = i / 720, rem = i - c * 720;
    int yy = rem / 36, xx2 = rem - yy * 36;
    int gy = tY0 + yy - 2, gx = xx2 - 2;
    sx[i] = (gy >= 0 && gy < 32 && gx >= 0 && gx < 32)
            ? xin[(long)img * 3072 + c * 1024 + gy * 32 + gx] : 0.f;
  }
  for (int i = tid; i < 864; i += 512) {
    int co = i & 31, kk = i >> 5;
    sw[kk * 32 + co] = cw1[(long)co * 27 + kk];
  }
  __syncthreads();

  #pragma unroll 1
  for (int p = 0; p < 2; ++p) {
    int px = p * 512 + tid;
    if (px < PXT) {
      int ry = px / PXW, rx = px - ry * PXW;
      int gy = tY0 + ry - 1, gx = rx - 1;
      if (gy >= 0 && gy < 32 && gx >= 0 && gx < 32) {
        #pragma unroll 1
        for (int half = 0; half < 2; ++half) {
          float acc[16];
          #pragma unroll
          for (int j = 0; j < 16; ++j) acc[j] = 0.f;
          #pragma unroll
          for (int c = 0; c < 3; ++c) {
            #pragma unroll
            for (int k = 0; k < 9; ++k) {
              int dy = k / 3, dx = k - 3 * (k / 3);
              float iv = sx[c * 720 + (ry + dy) * 36 + rx + dx];
              const float4* w4 = (const float4*)(sw + (c * 9 + k) * 32 + half * 16);
              #pragma unroll
              for (int q2 = 0; q2 < 4; ++q2) {
                float4 wv = w4[q2];
                acc[4 * q2 + 0] += iv * wv.x; acc[4 * q2 + 1] += iv * wv.y;
                acc[4 * q2 + 2] += iv * wv.z; acc[4 * q2 + 3] += iv * wv.w;
              }
            }
          }
          #pragma unroll
          for (int j2 = 0; j2 < 2; ++j2) {
            short8 hv, lv;
            #pragma unroll
            for (int j = 0; j < 8; ++j) {
              int co = half * 16 + j2 * 8 + j;
              float vv = fmaxf(acc[j2 * 8 + j] * A1p[co] + C1p[co], 0.f);
              unsigned short h = f2bf(vv);
              hv[j] = (short)h;
              lv[j] = (short)f2bf(vv - bf2f(h));
            }
            int plane = half * 2 + j2;
            *(short8*)(smem + plane * PLSTR + px * 8) = hv;
            *(short8*)(smem + (plane + 4) * PLSTR + px * 8) = lv;
          }
        }
      } else {
        short8 zz = {0, 0, 0, 0, 0, 0, 0, 0};
        #pragma unroll
        for (int cc = 0; cc < 8; ++cc)
          *(short8*)(smem + cc * PLSTR + px * 8) = zz;
      }
    }
  }
  __syncthreads();

  f32x4 acc[4][4];
  #pragma unroll
  for (int i = 0; i < 4; ++i)
    #pragma unroll
    for (int j = 0; j < 4; ++j) acc[i][j] = (f32x4){0.f, 0.f, 0.f, 0.f};

  for (int s = 0; s < 9; ++s) {
    const int ky = s / 3, kx = s - 3 * (s / 3);
    const long ub = ((long)(s * NF)) * 1024 + lane * 8;
    short8 bh[4], bl[4];
    #pragma unroll
    for (int nf = 0; nf < 4; ++nf) {
      bh[nf] = *(const short8*)(wPk + ub + nf * 1024);
      bl[nf] = *(const short8*)(wPk + ub + nf * 1024 + 512);
    }
    #pragma unroll
    for (int mf = 0; mf < 4; ++mf) {
      const int yoff = mf >> 1;
      const int xb = (mf & 1) * 16;
      const int y = w * 2 + yoff;
      const int pxa = (y + ky) * PXW + xb + kx + lx;
      short8 ah = *(const short8*)(smem + kg * PLSTR + pxa * 8);
      short8 al = *(const short8*)(smem + (kg + 4) * PLSTR + pxa * 8);
      #pragma unroll
      for (int nf = 0; nf < 4; ++nf)
        acc[mf][nf] = __builtin_amdgcn_mfma_f32_16x16x32_bf16(ah, bh[nf], acc[mf][nf], 0, 0, 0);
      #pragma unroll
      for (int nf = 0; nf < 4; ++nf)
        acc[mf][nf] = __builtin_amdgcn_mfma_f32_16x16x32_bf16(ah, bl[nf], acc[mf][nf], 0, 0, 0);
      #pragma unroll
      for (int nf = 0; nf < 4; ++nf)
        acc[mf][nf] = __builtin_amdgcn_mfma_f32_16x16x32_bf16(al, bh[nf], acc[mf][nf], 0, 0, 0);
    }
  }
  __syncthreads();

  float Ar[4], Cr[4];
  #pragma unroll
  for (int nf = 0; nf < 4; ++nf) {
    int co = nf * 16 + lx;
    Ar[nf] = Ap[co]; Cr[nf] = Cp[co];
  }

  unsigned short* slice = smem + w * 2048;
  const int py = (tY0 >> 1) + w;
  #pragma unroll
  for (int xf = 0; xf < 2; ++xf) {
    #pragma unroll
    for (int rp = 0; rp < 2; ++rp) {
      int ox = xf * 8 + 2 * kg + rp;
      #pragma unroll
      for (int nf = 0; nf < 4; ++nf) {
        float v0 = fmaxf(fmaxf(acc[xf][nf][2 * rp], acc[xf][nf][2 * rp + 1]),
                         fmaxf(acc[xf + 2][nf][2 * rp], acc[xf + 2][nf][2 * rp + 1]));
        float vv = fmaxf(v0 * Ar[nf] + Cr[nf], 0.f);
        unsigned short h = f2bf(vv);
        unsigned short l = f2bf(vv - bf2f(h));
        slice[(ox * 2 + 0) * 64 + nf * 16 + lx] = h;
        slice[(ox * 2 + 1) * 64 + nf * 16 + lx] = l;
      }
    }
  }
  #pragma unroll
  for (int v = 0; v < 4; ++v) {
    int hoff = lane * 8 + v * 512;
    int x2 = hoff >> 7, rem = hoff & 127;
    int seg = rem >> 6, inner = rem & 63;
    short8 d = *(const short8*)(slice + hoff);
    *(short8*)(outA + ((long)img * 256 + py * 16 + x2) * 128 + seg * 64 + inner) = d;
  }
}

// ---------------------------------------------------------------------------
// Fused conv3+conv4, software-pipelined (round-13 + T14):
//  - act2 staging double-buffered: cb=1 global loads issue during cb=0 MFMAs
//  - conv3/conv4 B fragments prefetched 1 chunk / 1 iteration ahead
// Accumulation order identical to round 13 -> bit-identical feats.
__global__ __launch_bounds__(512, 1) void convmf45_kernel(
    const unsigned short* __restrict__ act2,
    const unsigned short* __restrict__ wPk3, const float* __restrict__ A3p,
    const float* __restrict__ C3p,
    const unsigned short* __restrict__ wPk4, const float* __restrict__ A4p,
    const float* __restrict__ C4p, float* __restrict__ feats)
{
  constexpr int PLSTR3 = 2056;          // act3 plane stride (halves)
  constexpr int ZOFF = 32 * PLSTR3;     // zero page offset (65792)
  constexpr int PXW2 = 18, PXT2 = 324;  // act2 staging (halo'd)
  constexpr int PLSTR2 = PXT2 * 8 + 8;  // 2600
  constexpr int SBUF = 8 * PLSTR2;      // one staging buffer (20800 halves)
  __shared__ alignas(16) unsigned short smem[ZOFF + 64];   // 131,712 B

  const int nwg = gridDim.x;
  const int orig = blockIdx.x;
  const int q = nwg >> 3, r = nwg & 7;
  const int xcd = orig & 7, pos = orig >> 3;
  const int img = (xcd < r ? xcd * (q + 1) : r * (q + 1) + (xcd - r) * q) + pos;

  const int tid = threadIdx.x;
  const int lane = tid & 63;
  const int lx = lane & 15, kg = lane >> 4;
  const int w = tid >> 6;

  if (tid < 8) {
    short8 zz = {0, 0, 0, 0, 0, 0, 0, 0};
    *(short8*)(smem + ZOFF + tid * 8) = zz;
  }

  // ---------------- phase 1: conv3 (64->128), wave = rows 2w..2w+1, 128 co
  f32x4 acc3[2][8];
  #pragma unroll
  for (int i = 0; i < 2; ++i)
    #pragma unroll
    for (int j = 0; j < 8; ++j) acc3[i][j] = (f32x4){0.f, 0.f, 0.f, 0.f};

  float4 av[6];
  // LOADA2(cb): issue act2 tile global loads for block cb into av[]
  #define LOADA2(CB)                                                         \
    _Pragma("unroll")                                                        \
    for (int i = 0; i < 6; ++i) {                                            \
      int idx = tid + i * 512;                                               \
      if (idx < PXT2 * 8) {                                                  \
        int px = idx >> 3, c = idx & 7;                                      \
        int ry = px / PXW2, rx = px - ry * PXW2;                             \
        int gy = ry - 1, gx = rx - 1;                                        \
        float4 v = (float4){0.f, 0.f, 0.f, 0.f};                             \
        if (gy >= 0 && gy < 16 && gx >= 0 && gx < 16) {                      \
          int coff = (c < 4) ? ((CB) * 32 + c * 8) : (64 + (CB) * 32 + (c - 4) * 8); \
          v = *(const float4*)(act2 + ((long)img * 256 + gy * 16 + gx) * 128 + coff); \
        }                                                                    \
        av[i] = v;                                                           \
      }                                                                      \
    }
  #define WRITEA2(BUF)                                                       \
    _Pragma("unroll")                                                        \
    for (int i = 0; i < 6; ++i) {                                            \
      int idx = tid + i * 512;                                               \
      if (idx < PXT2 * 8) {                                                  \
        int px = idx >> 3, c = idx & 7;                                      \
        *(float4*)(smem + (BUF) * SBUF + c * PLSTR2 + px * 8) = av[i];       \
      }                                                                      \
    }

  LOADA2(0); WRITEA2(0);
  __syncthreads();
  LOADA2(1);   // cb=1 loads in flight, covered by cb=0 compute

  {
    short8 p3h[4], p3l[4];   // prefetched conv3 B chunk
    long ub = (long)lane * 8;          // ub(cb=0, s=0)
    #pragma unroll
    for (int nf = 0; nf < 4; ++nf) {
      p3h[nf] = *(const short8*)(wPk3 + ub + nf * 1024);
      p3l[nf] = *(const short8*)(wPk3 + ub + nf * 1024 + 512);
    }
    #pragma unroll 1
    for (int cb = 0; cb < 2; ++cb) {
      const unsigned short* sbase = smem + cb * SBUF;
      #pragma unroll 1
      for (int s = 0; s < 9; ++s) {
        const int ky = s / 3, kx = s - 3 * (s / 3);
        short8 ah[2], al[2];
        #pragma unroll
        for (int mf = 0; mf < 2; ++mf) {
          const int pxa = (w * 2 + mf + ky) * PXW2 + kx + lx;
          ah[mf] = *(const short8*)(sbase + kg * PLSTR2 + pxa * 8);
          al[mf] = *(const short8*)(sbase + (kg + 4) * PLSTR2 + pxa * 8);
        }
        // issue chunk-1 loads (covered by chunk-0 MFMAs)
        short8 c1h[4], c1l[4];
        #pragma unroll
        for (int nf = 0; nf < 4; ++nf) {
          c1h[nf] = *(const short8*)(wPk3 + ub + (4 + nf) * 1024);
          c1l[nf] = *(const short8*)(wPk3 + ub + (4 + nf) * 1024 + 512);
        }
        // chunk 0 MFMAs
        #pragma unroll
        for (int mf = 0; mf < 2; ++mf) {
          #pragma unroll
          for (int nf = 0; nf < 4; ++nf)
            acc3[mf][nf] = __builtin_amdgcn_mfma_f32_16x16x32_bf16(ah[mf], p3h[nf], acc3[mf][nf], 0, 0, 0);
          #pragma unroll
          for (int nf = 0; nf < 4; ++nf)
            acc3[mf][nf] = __builtin_amdgcn_mfma_f32_16x16x32_bf16(ah[mf], p3l[nf], acc3[mf][nf], 0, 0, 0);
          #pragma unroll
          for (int nf = 0; nf < 4; ++nf)
            acc3[mf][nf] = __builtin_amdgcn_mfma_f32_16x16x32_bf16(al[mf], p3h[nf], acc3[mf][nf], 0, 0, 0);
        }
        // preload next iteration's chunk 0 (covered by chunk-1 MFMAs)
        long ubn = (s < 8) ? (ub + 16384) : (ub - 122880);
        if (!(cb == 1 && s == 8)) {
          #pragma unroll
          for (int nf = 0; nf < 4; ++nf) {
            p3h[nf] = *(const short8*)(wPk3 + ubn + nf * 1024);
            p3l[nf] = *(const short8*)(wPk3 + ubn + nf * 1024 + 512);
          }
        }
        ub = ubn;
        // chunk 1 MFMAs
        #pragma unroll
        for (int mf = 0; mf < 2; ++mf) {
          #pragma unroll
          for (int nf = 0; nf < 4; ++nf)
            acc3[mf][4 + nf] = __builtin_amdgcn_mfma_f32_16x16x32_bf16(ah[mf], c1h[nf], acc3[mf][4 + nf], 0, 0, 0);
          #pragma unroll
          for (int nf = 0; nf < 4; ++nf)
            acc3[mf][4 + nf] = __builtin_amdgcn_mfma_f32_16x16x32_bf16(ah[mf], c1l[nf], acc3[mf][4 + nf], 0, 0, 0);
          #pragma unroll
          for (int nf = 0; nf < 4; ++nf)
            acc3[mf][4 + nf] = __builtin_amdgcn_mfma_f32_16x16x32_bf16(al[mf], c1h[nf], acc3[mf][4 + nf], 0, 0, 0);
        }
      }
      if (cb == 0) {
        WRITEA2(1);         // waits on cb=1 loads, writes second buffer
        __syncthreads();
      }
    }
  }
  __syncthreads();   // all conv3 staging reads complete

  // ---------------- phase 2: BN/ReLU + split-bf16 act3 -> LDS planes
  #pragma unroll
  for (int mf = 0; mf < 2; ++mf) {
    int y = w * 2 + mf;
    #pragma unroll
    for (int rr = 0; rr < 4; ++rr) {
      int px = y * 16 + 4 * kg + rr;
      #pragma unroll
      for (int nf = 0; nf < 8; ++nf) {
        int co = nf * 16 + lx;
        float vv = fmaxf(acc3[mf][nf][rr] * A3p[co] + C3p[co], 0.f);
        unsigned short h = f2bf(vv);
        unsigned short l = f2bf(vv - bf2f(h));
        int plane = co >> 3, j = co & 7;
        smem[plane * PLSTR3 + px * 8 + j] = h;
        smem[(plane + 16) * PLSTR3 + px * 8 + j] = l;
      }
    }
  }
  __syncthreads();

  // ---------------- phase 3: conv4 (128->256), pipelined B, no staging
  const int pxg = w >> 1;
  const int cog = w & 1;

  f32x4 acc[4][8];
  #pragma unroll
  for (int i = 0; i < 4; ++i)
    #pragma unroll
    for (int j = 0; j < 8; ++j) acc[i][j] = (f32x4){0.f, 0.f, 0.f, 0.f};

  {
    short8 p4h[4], p4l[4];   // prefetched conv4 B chunk 0
    long ub = ((long)cog * 8) * 1024 + lane * 8;   // ub(cb=0, s=0)
    #pragma unroll
    for (int nf = 0; nf < 4; ++nf) {
      p4h[nf] = *(const short8*)(wPk4 + ub + nf * 1024);
      p4l[nf] = *(const short8*)(wPk4 + ub + nf * 1024 + 512);
    }
    #pragma unroll 1
    for (int cb = 0; cb < 4; ++cb) {
      #pragma unroll 1
      for (int s = 0; s < 9; ++s) {
        const int ky = s / 3, kx = s - 3 * (s / 3);
        short8 ah[4], al[4];
        #pragma unroll
        for (int mf = 0; mf < 4; ++mf) {
          int gy = pxg * 4 + mf + ky - 1;
          int gxx = lx + kx - 1;
          bool ok = (gy >= 0) && (gy < 16) && (gxx >= 0) && (gxx < 16);
          int pxo = (gy * 16 + gxx) * 8;
          int offH = ok ? ((cb * 4 + kg) * PLSTR3 + pxo) : ZOFF;
          int offL = ok ? ((16 + cb * 4 + kg) * PLSTR3 + pxo) : ZOFF;
          ah[mf] = *(const short8*)(smem + offH);
          al[mf] = *(const short8*)(smem + offL);
        }
        // issue chunk-1 loads (covered by chunk-0 MFMAs)
        short8 c1h[4], c1l[4];
        #pragma unroll
        for (int nf = 0; nf < 4; ++nf) {
          c1h[nf] = *(const short8*)(wPk4 + ub + (4 + nf) * 1024);
          c1l[nf] = *(const short8*)(wPk4 + ub + (4 + nf) * 1024 + 512);
        }
        // chunk 0 MFMAs: acc[mf][0..3]
        #pragma unroll
        for (int mf = 0; mf < 4; ++mf) {
          #pragma unroll
          for (int nf = 0; nf < 4; ++nf)
            acc[mf][nf] = __builtin_amdgcn_mfma_f32_16x16x32_bf16(ah[mf], p4h[nf], acc[mf][nf], 0, 0, 0);
          #pragma unroll
          for (int nf = 0; nf < 4; ++nf)
            acc[mf][nf] = __builtin_amdgcn_mfma_f32_16x16x32_bf16(ah[mf], p4l[nf], acc[mf][nf], 0, 0, 0);
          #pragma unroll
          for (int nf = 0; nf < 4; ++nf)
            acc[mf][nf] = __builtin_amdgcn_mfma_f32_16x16x32_bf16(al[mf], p4h[nf], acc[mf][nf], 0, 0, 0);
        }
        // preload next iteration's chunk 0 (covered by chunk-1 MFMAs)
        long ubn = (s < 8) ? (ub + 65536) : (ub - 507904);
        if (!(cb == 3 && s == 8)) {
          #pragma unroll
          for (int nf = 0; nf < 4; ++nf) {
            p4h[nf] = *(const short8*)(wPk4 + ubn + nf * 1024);
            p4l[nf] = *(const short8*)(wPk4 + ubn + nf * 1024 + 512);
          }
        }
        ub = ubn;
        // chunk 1 MFMAs: acc[mf][4..7]
        #pragma unroll
        for (int mf = 0; mf < 4; ++mf) {
          #pragma unroll
          for (int nf = 0; nf < 4; ++nf)
            acc[mf][4 + nf] = __builtin_amdgcn_mfma_f32_16x16x32_bf16(ah[mf], c1h[nf], acc[mf][4 + nf], 0, 0, 0);
          #pragma unroll
          for (int nf = 0; nf < 4; ++nf)
            acc[mf][4 + nf] = __builtin_amdgcn_mfma_f32_16x16x32_bf16(ah[mf], c1l[nf], acc[mf][4 + nf], 0, 0, 0);
          #pragma unroll
          for (int nf = 0; nf < 4; ++nf)
            acc[mf][4 + nf] = __builtin_amdgcn_mfma_f32_16x16x32_bf16(al[mf], c1h[nf], acc[mf][4 + nf], 0, 0, 0);
        }
      }
    }
  }
  __syncthreads();   // all conv4 LDS reads complete before sR reuse

  // epilogue: 2x2 maxpool + BN/ReLU + global average -> feats
  float psum[8];
  #pragma unroll
  for (int j = 0; j < 8; ++j) psum[j] = 0.f;
  #pragma unroll
  for (int j = 0; j < 8; ++j) {
    int co = (cog * 8 + j) * 16 + lx;
    float Ar = A4p[co], Cr = C4p[co];
    #pragma unroll
    for (int u = 0; u < 2; ++u) {
      #pragma unroll
      for (int v = 0; v < 2; ++v) {
        float vm = fmaxf(fmaxf(acc[2 * u][j][2 * v], acc[2 * u][j][2 * v + 1]),
                         fmaxf(acc[2 * u + 1][j][2 * v], acc[2 * u + 1][j][2 * v + 1]));
        psum[j] += fmaxf(vm * Ar + Cr, 0.f);
      }
    }
  }
  #pragma unroll
  for (int j = 0; j < 8; ++j) {
    psum[j] += __shfl_xor(psum[j], 16);
    psum[j] += __shfl_xor(psum[j], 32);
  }
  float* sR = (float*)smem;
  if (kg == 0) {
    #pragma unroll
    for (int j = 0; j < 8; ++j) sR[w * 128 + j * 16 + lx] = psum[j];
  }
  __syncthreads();
  if (tid < 256) {
    int cogT = tid >> 7, cl = tid & 127;
    float s = 0.f;
    #pragma unroll
    for (int p = 0; p < 4; ++p) s += sR[(p * 2 + cogT) * 128 + cl];
    feats[(long)img * 256 + tid] = s * (1.f / 64.f);
  }
  #undef LOADA2
  #undef WRITEA2
}

// ---------------------------------------------------------------------------
// heads / sort / routing / combine (unchanged)
__global__ __launch_bounds__(256) void heads2_kernel(
    const float* __restrict__ feats, const float* __restrict__ gw1,
    const float* __restrict__ gb1, const float* __restrict__ gw2,
    const float* __restrict__ gb2, const float* __restrict__ clsw,
    const float* __restrict__ clsb, const float* __restrict__ usage,
    float* __restrict__ logits_e, float* __restrict__ rs_out)
{
  __shared__ float sF[64 * 257];
  __shared__ float sLg[4 * 64 * 10];
  __shared__ float sRed[4 * 64];
  const int tid = threadIdx.x;
  const int b0 = blockIdx.x * 64;
  const int e  = blockIdx.y;

  for (int idx = tid; idx < 64 * 64; idx += 256) {
    int t = idx >> 6, dg = idx & 63;
    float4 v = ((const float4*)(feats + (long)(b0 + t) * 256))[dg];
    float* p = sF + t * 257 + dg * 4;
    p[0] = v.x; p[1] = v.y; p[2] = v.z; p[3] = v.w;
  }
  __syncthreads();

  const int t  = tid & 63;
  const int hw = __builtin_amdgcn_readfirstlane(tid >> 6);

  {
    float acc[10];
    #pragma unroll
    for (int c = 0; c < 10; ++c) acc[c] = 0.f;
    const float* fp = sF + t * 257 + hw * 64;
    const float* cw = clsw + (long)e * 2560 + hw * 64;
    for (int dd = 0; dd < 64; ++dd) {
      float f = fp[dd];
      #pragma unroll
      for (int c = 0; c < 10; ++c) acc[c] += f * cw[c * 256 + dd];
    }
    #pragma unroll
    for (int c = 0; c < 10; ++c) sLg[(hw * 64 + t) * 10 + c] = acc[c];
  }
  {
    float gacc[32];
    #pragma unroll
    for (int j = 0; j < 32; ++j) gacc[j] = 0.f;
    const float* wb = gw1 + ((long)e * 256) * 128 + hw * 32;
    const float* fp = sF + t * 257;
    for (int d = 0; d < 256; ++d) {
      float f = fp[d];
      const float4* w4 = (const float4*)(wb + (long)d * 128);
      #pragma unroll
      for (int qq = 0; qq < 8; ++qq) {
        float4 wv = w4[qq];
        gacc[4 * qq + 0] += f * wv.x; gacc[4 * qq + 1] += f * wv.y;
        gacc[4 * qq + 2] += f * wv.z; gacc[4 * qq + 3] += f * wv.w;
      }
    }
    float s = 0.f;
    const float* b1 = gb1 + e * 128 + hw * 32;
    const float* w2 = gw2 + e * 128 + hw * 32;
    #pragma unroll
    for (int j = 0; j < 32; ++j) s += fmaxf(gacc[j] + b1[j], 0.f) * w2[j];
    sRed[hw * 64 + t] = s;
  }
  __syncthreads();

  if (tid < 64) {
    float es = (sRed[t] + sRed[64 + t] + sRed[128 + t] + sRed[192 + t] + gb2[e]) * 0.5f;
    float lg[10];
    #pragma unroll
    for (int c = 0; c < 10; ++c)
      lg[c] = sLg[t * 10 + c] + sLg[(64 + t) * 10 + c]
            + sLg[(128 + t) * 10 + c] + sLg[(192 + t) * 10 + c] + clsb[e * 10 + c];
    float mx = lg[0];
    #pragma unroll
    for (int c = 1; c < 10; ++c) mx = fmaxf(mx, lg[c]);
    float S = 0.f, ps[10];
    #pragma unroll
    for (int c = 0; c < 10; ++c) { ps[c] = expf(lg[c] - mx); S += ps[c]; }
    float inv = 1.f / S, ent = 0.f;
    #pragma unroll
    for (int c = 0; c < 10; ++c) { float p = ps[c] * inv; ent -= p * logf(fmaxf(p, 1e-12f)); }
    float rsv = 0.6f * es + 0.4f * (-ent) - 2.0f * usage[e];
    rs_out[(long)(b0 + t) * 16 + e] = rsv;
    #pragma unroll
    for (int c = 0; c < 10; ++c)
      logits_e[((long)(b0 + t) * 16 + e) * 10 + c] = lg[c];
  }
}

__global__ __launch_bounds__(1024) void sort_kernel(
    const float* __restrict__ rs, unsigned* __restrict__ sortedIdx)
{
  __shared__ unsigned long long sk[2048];
  const int e = blockIdx.x;
  const unsigned tid = threadIdx.x;
  for (int i = tid; i < 2048; i += 1024) {
    float f = rs[(long)i * 16 + e];
    unsigned u = __float_as_uint(f);
    u ^= (u >> 31) ? 0xFFFFFFFFu : 0x80000000u;
    sk[i] = ((unsigned long long)(~u) << 32) | (unsigned)i;
  }
  for (unsigned k = 2; k <= 2048; k <<= 1) {
    for (unsigned j = k >> 1; j > 0; j >>= 1) {
      __syncthreads();
      unsigned i = ((tid & ~(j - 1)) << 1) | (tid & (j - 1));
      unsigned p = i | j;
      bool asc = ((i & k) == 0);
      unsigned long long a = sk[i], b = sk[p];
      if ((a > b) == asc) { sk[i] = b; sk[p] = a; }
    }
  }
  __syncthreads();
  for (int i = tid; i < 2048; i += 1024)
    sortedIdx[(long)e * 2048 + i] = (unsigned)(sk[i] & 0xFFFFFFFFull);
}

__global__ __launch_bounds__(64) void routing2_kernel(
    const unsigned* __restrict__ sortedIdx, const float* __restrict__ rs,
    unsigned* __restrict__ dmaskOut)
{
  __shared__ unsigned char sAvail[2048];
  __shared__ unsigned sDm[2048];
  __shared__ int sLoads[16];
  const int lane = threadIdx.x;
  for (int i = lane; i < 2048; i += 64) { sAvail[i] = 1; sDm[i] = 0; }
  if (lane < 16) sLoads[lane] = 0;
  __syncthreads();

  int vc = 2048;
  for (int it = 0; it < 3; ++it) {
    for (int j = 0; j < 16; ++j) {
      int lj = sLoads[j];
      int rc = 256 - lj; if (rc < 0) rc = 0;
      int ntc = 0;
      if (rc > 0 && vc > 0) {
        int a = rc < vc ? rc : vc;
        int b2 = vc < 102 ? vc : 102;
        ntc = a > b2 ? a : b2;
      }
      if (ntc > 0) {
        const unsigned* se = sortedIdx + (long)j * 2048;
        int taken = 0;
        for (int base = 0; base < 2048; base += 64) {
          if (taken >= ntc) break;
          unsigned tok = se[base + lane];
          int fl = sAvail[tok] ? 1 : 0;
          unsigned long long bm = __ballot(fl);
          int pre = taken + __popcll(bm & ((1ull << lane) - 1ull));
          if (fl && pre < ntc) { sAvail[tok] = 0; sDm[tok] |= (1u << j); }
          taken += (int)__popcll(bm);
          __syncthreads();
        }
        if (lane == 0) sLoads[j] = lj + ntc;
        vc -= ntc;
        __syncthreads();
      }
    }
  }

  if (vc > 0) {
    if (lane == 0) {
      for (int i = 0; i < 2048; ++i) {
        if (!sAvail[i]) continue;
        float s0 = -3.4e38f, s1 = s0, s2 = s0; int e0 = 0, e1 = 0, e2 = 0;
        for (int e = 0; e < 16; ++e) {
          float s = rs[i * 16 + e];
          if (s > s0)      { s2 = s1; e2 = e1; s1 = s0; e1 = e0; s0 = s; e0 = e; }
          else if (s > s1) { s2 = s1; e2 = e1; s1 = s;  e1 = e; }
          else if (s > s2) { s2 = s;  e2 = e; }
        }
        int best = e0, bl = sLoads[e0];
        if (sLoads[e1] < bl) { best = e1; bl = sLoads[e1]; }
        if (sLoads[e2] < bl) { best = e2; bl = sLoads[e2]; }
        sDm[i] |= (1u << best);
        sLoads[best] += 1;
      }
    }
    __syncthreads();
  }

  for (int i = lane; i < 2048; i += 64) dmaskOut[i] = sDm[i];
}

__global__ __launch_bounds__(256) void combine_kernel(
    const unsigned* __restrict__ dmask, const float* __restrict__ rs,
    const float* __restrict__ L, float* __restrict__ out, float* __restrict__ Dout)
{
  int i = blockIdx.x * 256 + threadIdx.x;
  if (i >= 2048) return;
  unsigned dm = dmask[i];
  float r[16];
  #pragma unroll
  for (int e = 0; e < 16; ++e) r[e] = rs[i * 16 + e];
  float mx = -3.4e38f;
  #pragma unroll
  for (int e = 0; e < 16; ++e) {
    float v = ((dm >> e) & 1u) ? r[e] : 0.0f;
    mx = fmaxf(mx, v);
  }
  float w[16], S = 0.f;
  #pragma unroll
  for (int e = 0; e < 16; ++e) {
    w[e] = ((dm >> e) & 1u) ? expf(r[e] - mx) : 0.0f;
    S += w[e];
  }
  float inv = 1.f / S;
  #pragma unroll
  for (int c = 0; c < 10; ++c) {
    float a = 0.f;
    #pragma unroll
    for (int e = 0; e < 16; ++e) a += w[e] * L[((long)i * 16 + e) * 10 + c];
    out[i * 10 + c] = a * inv;
  }
  #pragma unroll
  for (int e = 0; e < 16; ++e)
    Dout[(long)i * 16 + e] = ((dm >> e) & 1u) ? 1.0f : 0.0f;
}

// ---------------------------------------------------------------------------
extern "C" void kernel_launch(void* const* d_in, const int* in_sizes, int n_in,
                              void* d_out, int out_size, void* d_ws, size_t ws_size,
                              hipStream_t stream)
{
  const float* x    = (const float*)d_in[0];
  const float* cw1  = (const float*)d_in[1];
  const float* cb1  = (const float*)d_in[2];
  const float* g1   = (const float*)d_in[3];
  const float* be1  = (const float*)d_in[4];
  const float* m1   = (const float*)d_in[5];
  const float* v1   = (const float*)d_in[6];
  const float* cw2  = (const float*)d_in[7];
  const float* cb2  = (const float*)d_in[8];
  const float* g2   = (const float*)d_in[9];
  const float* be2  = (const float*)d_in[10];
  const float* m2   = (const float*)d_in[11];
  const float* v2   = (const float*)d_in[12];
  const float* cw3  = (const float*)d_in[13];
  const float* cb3  = (const float*)d_in[14];
  const float* g3   = (const float*)d_in[15];
  const float* be3  = (const float*)d_in[16];
  const float* m3   = (const float*)d_in[17];
  const float* v3   = (const float*)d_in[18];
  const float* cw4  = (const float*)d_in[19];
  const float* cb4  = (const float*)d_in[20];
  const float* g4   = (const float*)d_in[21];
  const float* be4  = (const float*)d_in[22];
  const float* m4   = (const float*)d_in[23];
  const float* v4   = (const float*)d_in[24];
  const float* gw1  = (const float*)d_in[25];
  const float* gb1  = (const float*)d_in[26];
  const float* gw2  = (const float*)d_in[27];
  const float* gb2  = (const float*)d_in[28];
  const float* clsw = (const float*)d_in[29];
  const float* clsb = (const float*)d_in[30];
  const float* usage = (const float*)d_in[31];

  float* out = (float*)d_out;
  float* ws  = (float*)d_ws;

  float* A1 = ws + 0;   float* C1 = ws + 32;
  float* A2 = ws + 64;  float* C2 = ws + 128;
  float* A3 = ws + 192; float* C3 = ws + 320;
  float* A4 = ws + 448; float* C4 = ws + 704;
  float* feats   = ws + 1024;                       // 2048*256
  float* logitsE = ws + 525312;                     // 2048*16*10
  unsigned* sortedIdx = (unsigned*)(ws + 852992);   // 16*2048
  unsigned* dmask     = (unsigned*)(ws + 885760);   // 2048
  unsigned short* wPk2 = (unsigned short*)(ws + 887808);   // 36 units  * 1024 halves
  unsigned short* wPk3 = (unsigned short*)(ws + 906240);   // 144 units * 1024
  unsigned short* wPk4 = (unsigned short*)(ws + 979968);   // 576 units * 1024
  const long bufBase = 1274880;

  long wsFloats = (long)(ws_size / 4);
  long availF = wsFloats - bufBase;
  long chunkL = availF / 16384;   // per-img: act2 only (16384 floats)
  int chunk = (int)(chunkL < 1 ? 1 : (chunkL > 2048 ? 2048 : chunkL));

  bnprep_kernel<<<1, 256, 0, stream>>>(g1, be1, m1, v1, cb1, A1, C1, 32);
  bnprep_kernel<<<1, 256, 0, stream>>>(g2, be2, m2, v2, cb2, A2, C2, 64);
  bnprep_kernel<<<1, 256, 0, stream>>>(g3, be3, m3, v3, cb3, A3, C3, 128);
  bnprep_kernel<<<1, 256, 0, stream>>>(g4, be4, m4, v4, cb4, A4, C4, 256);
  wprep2_kernel<<<(2304 + 255) / 256, 256, 0, stream>>>(cw2, wPk2, 64, 32);
  wprep2_kernel<<<(9216 + 255) / 256, 256, 0, stream>>>(cw3, wPk3, 128, 64);
  wprep2_kernel<<<(36864 + 255) / 256, 256, 0, stream>>>(cw4, wPk4, 256, 128);

  unsigned short* act2buf = (unsigned short*)(ws + bufBase);

  for (int ib = 0; ib < 2048; ib += chunk) {
    int n = 2048 - ib; if (n > chunk) n = chunk;
    conv12_kernel<<<dim3(n * 2), 512, 0, stream>>>(
        x + (long)ib * 3072, cw1, A1, C1, wPk2, A2, C2, act2buf);
    convmf45_kernel<<<dim3(n), 512, 0, stream>>>(
        act2buf, wPk3, A3, C3, wPk4, A4, C4, feats + (long)ib * 256);
  }

  float* rsOut = out + 20480;
  heads2_kernel<<<dim3(32, 16), 256, 0, stream>>>(feats, gw1, gb1, gw2, gb2,
                                                  clsw, clsb, usage, logitsE, rsOut);
  sort_kernel<<<16, 1024, 0, stream>>>(rsOut, sortedIdx);
  routing2_kernel<<<1, 64, 0, stream>>>(sortedIdx, rsOut, dmask);
  combine_kernel<<<8, 256, 0, stream>>>(dmask, rsOut, logitsE, out, out + 53248);
}